// Round 12
// baseline (1158.669 us; speedup 1.0000x reference)
//
#include <hip/hip_runtime.h>

#define B_     2
#define L_     4096
#define DM     1024
#define DI     2048
#define NH     16
#define HD     128
#define NS     64      // D_STATE
#define T_     256     // CHUNK
#define NC     16      // L_/T_
#define CONVD  2176    // DI + 2*NS
#define DPROJ  4240    // DI + CONVD + NH
#define NPADIN 4352    // 34*128, padded W_in rows

typedef __attribute__((ext_vector_type(8))) short bf16x8;
typedef __attribute__((ext_vector_type(4))) float f32x4;

// split fp32 -> bf16 hi (RNE) + bf16 lo (truncated residual)
__device__ __forceinline__ void bsplit(float x, unsigned short& h, unsigned short& l) {
    unsigned u = __float_as_uint(x);
    unsigned t = u + 0x7FFFu + ((u >> 16) & 1u);
    h = (unsigned short)(t >> 16);
    float lo = x - __uint_as_float(t & 0xFFFF0000u);
    l = (unsigned short)(__float_as_uint(lo) >> 16);
}

// ---------------- split fp32 matrix -> bf16 hi/lo, zero-padding tail rows ----------------
__global__ __launch_bounds__(256) void split_pad(
    const float* __restrict__ W, unsigned short* __restrict__ Wh,
    unsigned short* __restrict__ Wl, int srcN4, int dstN4)
{
    int i = blockIdx.x * 256 + threadIdx.x;
    if (i >= dstN4) return;
    ushort4 h = {0,0,0,0}, l = {0,0,0,0};
    if (i < srcN4) {
        float4 v = *(const float4*)(W + (size_t)i * 4);
        bsplit(v.x, h.x, l.x); bsplit(v.y, h.y, l.y);
        bsplit(v.z, h.z, l.z); bsplit(v.w, h.w, l.w);
    }
    *(ushort4*)(Wh + (size_t)i * 4) = h;
    *(ushort4*)(Wl + (size_t)i * 4) = l;
}

// ---------------- LDS-staged bf16x3 GEMM, pre-split A and W (r10 measured-good) ----------------
// C[m,n] = sum_k A[m,k]*W[n,k]; 128x128 tile, BK=32, 4 waves (64x64 each),
// padded [128][40] ushort LDS, staging = pure 16B copies. 40KB LDS, 4 blocks/CU target.
__global__ __launch_bounds__(256, 4) void mfma_gemm_lds(
    const unsigned short* __restrict__ Ah, const unsigned short* __restrict__ Al,
    long arow, const unsigned short* __restrict__ Wh, const unsigned short* __restrict__ Wl,
    float* __restrict__ C, int N, int K, int ldc, int nyt)
{
    __shared__ unsigned short AhL[128 * 40];
    __shared__ unsigned short AlL[128 * 40];
    __shared__ unsigned short BhL[128 * 40];
    __shared__ unsigned short BlL[128 * 40];

    // XCD-chunked column-major tiling
    int NB = gridDim.x;
    int bid = blockIdx.x;
    int t = (bid & 7) * (NB >> 3) + (bid >> 3);
    int xt = t / nyt, yt = t % nyt;
    int tid = threadIdx.x;
    int lane = tid & 63, w = tid >> 6;
    int m0 = yt * 128, n0 = xt * 128;
    int mblk = (w >> 1) * 64, nblk = (w & 1) * 64;
    int fr = lane & 15;
    int fk = (lane >> 4) * 8;

    int sr0 = tid >> 2, sc0 = (tid & 3) * 8;
    int sr1 = (tid + 256) >> 2, sc1 = ((tid + 256) & 3) * 8;

    f32x4 acc[4][4];
    #pragma unroll
    for (int i = 0; i < 4; i++)
        #pragma unroll
        for (int j = 0; j < 4; j++) acc[i][j] = (f32x4){0.f, 0.f, 0.f, 0.f};

    int nk = K >> 5;
    for (int ks = 0; ks < nk; ks++) {
        int k0 = ks << 5;
        __syncthreads();
        {
            size_t a0 = (size_t)(m0 + sr0) * arow + k0 + sc0;
            size_t a1 = (size_t)(m0 + sr1) * arow + k0 + sc1;
            size_t b0 = (size_t)(n0 + sr0) * K + k0 + sc0;
            size_t b1 = (size_t)(n0 + sr1) * K + k0 + sc1;
            *(uint4*)&AhL[sr0 * 40 + sc0] = *(const uint4*)(Ah + a0);
            *(uint4*)&AhL[sr1 * 40 + sc1] = *(const uint4*)(Ah + a1);
            *(uint4*)&AlL[sr0 * 40 + sc0] = *(const uint4*)(Al + a0);
            *(uint4*)&AlL[sr1 * 40 + sc1] = *(const uint4*)(Al + a1);
            *(uint4*)&BhL[sr0 * 40 + sc0] = *(const uint4*)(Wh + b0);
            *(uint4*)&BhL[sr1 * 40 + sc1] = *(const uint4*)(Wh + b1);
            *(uint4*)&BlL[sr0 * 40 + sc0] = *(const uint4*)(Wl + b0);
            *(uint4*)&BlL[sr1 * 40 + sc1] = *(const uint4*)(Wl + b1);
        }
        __syncthreads();

        bf16x8 ah[4], al[4], bh[4], bl[4];
        #pragma unroll
        for (int tt = 0; tt < 4; tt++) {
            ah[tt] = *(const bf16x8*)&AhL[(mblk + tt*16 + fr) * 40 + fk];
            al[tt] = *(const bf16x8*)&AlL[(mblk + tt*16 + fr) * 40 + fk];
            bh[tt] = *(const bf16x8*)&BhL[(nblk + tt*16 + fr) * 40 + fk];
            bl[tt] = *(const bf16x8*)&BlL[(nblk + tt*16 + fr) * 40 + fk];
        }
        #pragma unroll
        for (int mt = 0; mt < 4; mt++)
            #pragma unroll
            for (int nt = 0; nt < 4; nt++) {
                f32x4 a = acc[mt][nt];
                a = __builtin_amdgcn_mfma_f32_16x16x32_bf16(al[mt], bh[nt], a, 0, 0, 0);
                a = __builtin_amdgcn_mfma_f32_16x16x32_bf16(ah[mt], bl[nt], a, 0, 0, 0);
                a = __builtin_amdgcn_mfma_f32_16x16x32_bf16(ah[mt], bh[nt], a, 0, 0, 0);
                acc[mt][nt] = a;
            }
    }

    int crow = (lane >> 4) * 4;
    #pragma unroll
    for (int mt = 0; mt < 4; mt++) {
        int rbase = m0 + mblk + mt*16 + crow;
        #pragma unroll
        for (int nt = 0; nt < 4; nt++) {
            int col = n0 + nblk + nt*16 + fr;
            if (col < N) {
                #pragma unroll
                for (int i = 0; i < 4; i++)
                    C[(size_t)(rbase + i) * ldc + col] = acc[mt][nt][i];
            }
        }
    }
}

// ---------------- depthwise causal conv (width 4) + bias + silu; one batch ----------------
__global__ void conv_silu(const float* __restrict__ proj, const float* __restrict__ w,
                          const float* __restrict__ bias, float* __restrict__ xbc)
{
    size_t idx = (size_t)blockIdx.x * 256 + threadIdx.x;
    if (idx >= (size_t)L_ * CONVD) return;
    int c = (int)(idx % CONVD);
    int l = (int)(idx / CONVD);
    float acc = bias[c];
    #pragma unroll
    for (int j = 0; j < 4; j++) {
        int ll = l - 3 + j;
        if (ll >= 0)
            acc = fmaf(proj[(size_t)ll * DPROJ + DI + c], w[c*4+j], acc);
    }
    acc = acc / (1.f + expf(-acc));   // silu
    xbc[(size_t)l * CONVD + c] = acc;
}

// ---------------- dt = softplus(dt_raw + bias); acs = cumsum(dt*A) within 256-chunk ----------------
__global__ __launch_bounds__(256) void dt_scan(
    const float* __restrict__ proj, const float* __restrict__ A_log,
    const float* __restrict__ dt_bias, float* __restrict__ dt_t, float* __restrict__ acs)
{
    int blk = blockIdx.x;            // c*NH + h
    int h = blk % NH;
    int c = blk / NH;
    int t = threadIdx.x;
    size_t row = (size_t)(c * T_ + t);
    float raw = proj[row * DPROJ + DI + CONVD + h] + dt_bias[h];
    float dtv = (raw > 20.f) ? raw : log1pf(expf(raw));
    float Ah = -expf(A_log[h]);
    __shared__ float buf[T_];
    buf[t] = dtv * Ah;
    __syncthreads();
    for (int off = 1; off < T_; off <<= 1) {
        float add = (t >= off) ? buf[t - off] : 0.f;
        __syncthreads();
        buf[t] += add;
        __syncthreads();
    }
    size_t o = (size_t)blk * T_ + t;
    dt_t[o] = dtv;
    acs[o]  = buf[t];
}

// ---------------- per-256-chunk states[p][n] = sum_t x[t,p]*B[t,n]*exp(acs_last-acs[t])*dt[t] ----------------
__global__ __launch_bounds__(256) void chunk_states(
    const float* __restrict__ xbc, const float* __restrict__ dt_t,
    const float* __restrict__ acs, float* __restrict__ states)
{
    int bid = blockIdx.x;            // XCD swizzle (grid 256)
    int blk = (bid & 7) * 32 + (bid >> 3);
    int h = blk % NH;
    int c = blk / NH;
    int tid = threadIdx.x;
    __shared__ float coef[T_];
    __shared__ __align__(16) float xs[32][HD];
    __shared__ float Bs[32][NS + 1];
    {
        size_t o = (size_t)blk * T_;
        float last = acs[o + T_ - 1];
        coef[tid] = expf(last - acs[o + tid]) * dt_t[o + tid];
    }
    __syncthreads();
    int tx = tid % 16;
    int ty = tid / 16;
    float acc[8][4];
    #pragma unroll
    for (int i = 0; i < 8; i++)
        #pragma unroll
        for (int j = 0; j < 4; j++) acc[i][j] = 0.f;
    size_t rowbase = (size_t)(c * T_);
    for (int t0 = 0; t0 < T_; t0 += 32) {
        #pragma unroll
        for (int i = 0; i < 4; i++) {
            int idx = tid + 256 * i;
            int r = idx >> 5, cv = idx & 31;
            float4 v = *(const float4*)(xbc + (rowbase + t0 + r) * CONVD + h * HD + cv * 4);
            *(float4*)&xs[r][cv * 4] = v;
        }
        #pragma unroll
        for (int i = 0; i < 2; i++) {
            int idx = tid + 256 * i;
            int r = idx >> 4, cv = idx & 15;
            float4 v = *(const float4*)(xbc + (rowbase + t0 + r) * CONVD + DI + cv * 4);
            float wc = coef[t0 + r];
            Bs[r][cv*4+0] = v.x * wc; Bs[r][cv*4+1] = v.y * wc;
            Bs[r][cv*4+2] = v.z * wc; Bs[r][cv*4+3] = v.w * wc;
        }
        __syncthreads();
        #pragma unroll
        for (int tt = 0; tt < 32; tt++) {
            float xv[8], bv[4];
            #pragma unroll
            for (int i = 0; i < 8; i++) xv[i] = xs[tt][ty*8+i];
            #pragma unroll
            for (int j = 0; j < 4; j++) bv[j] = Bs[tt][tx*4+j];
            #pragma unroll
            for (int i = 0; i < 8; i++)
                #pragma unroll
                for (int j = 0; j < 4; j++)
                    acc[i][j] = fmaf(xv[i], bv[j], acc[i][j]);
        }
        __syncthreads();
    }
    size_t base = (size_t)blk * HD * NS;
    #pragma unroll
    for (int i = 0; i < 8; i++)
        #pragma unroll
        for (int j = 0; j < 4; j++)
            states[base + (size_t)(ty*8+i) * NS + tx*4+j] = acc[i][j];
}

// ---------------- in-place inter-chunk recurrence: states[c] <- prev[c] ----------------
__global__ __launch_bounds__(256) void prev_rec(
    float* __restrict__ states, const float* __restrict__ acs)
{
    int blk = blockIdx.x;          // h*4 + pq
    int pq = blk % 4;
    int h = blk / 4;
    int tid = threadIdx.x;
    int s = tid * 8;
    int p = pq * 32 + s / NS;
    int n0 = s % NS;
    float run[8];
    #pragma unroll
    for (int j = 0; j < 8; j++) run[j] = 0.f;
    for (int c = 0; c < NC; c++) {
        size_t ch = (size_t)(c * NH + h);
        size_t off = ch * HD * NS + (size_t)p * NS + n0;
        float sv[8];
        #pragma unroll
        for (int j = 0; j < 8; j++) sv[j] = states[off + j];
        #pragma unroll
        for (int j = 0; j < 8; j++) states[off + j] = run[j];
        float f = expf(acs[ch * T_ + T_ - 1]);
        #pragma unroll
        for (int j = 0; j < 8; j++) run[j] = sv[j] + f * run[j];
    }
}

// ---------------- fused Y: block per (chunk,head,p-half); H[64][64] in LDS ----------------
// 2-way p-split -> grid 512 -> 2 blocks/CU (latency hiding). B/C staged twice per (c,h)
// but XCD-swizzle keeps both blocks of a (c,h) on one XCD -> L2 hits.
// Gated output written as SPLIT bf16 into proj's dead xBC columns.
__global__ __launch_bounds__(512, 4) void y_chunk(
    const float* __restrict__ xbc, const float* __restrict__ dt_t,
    const float* __restrict__ acs, const float* __restrict__ prev,
    const float* __restrict__ D_skip, float* zy /* = proj */)
{
    int bid = blockIdx.x;
    int l = (bid & 7) * 64 + (bid >> 3);   // XCD swizzle (512%8==0, bijective)
    int ph = l & 1;                        // p half: cols ph*64..ph*64+63
    int ch = l >> 1;
    int h = ch & 15;
    int c = ch >> 4;
    int tid = threadIdx.x;
    int pbase = ph * 64;

    __shared__ __align__(16) float smem[12288];   // 48 KB
    float* H     = smem;            // [64][65] = 4160
    float* Cs    = smem + 4160;     // [32][68] = 2176
    float* Bsh   = smem + 6336;     // [32][68] = 2176
    float* xs    = smem + 8512;     // [32][68] = 2176
    float* Ss    = smem + 10688;    // [32][33] = 1056
    float* acs_s = smem + 11744;    // [256]
    float* dts   = smem + 12000;    // [256]
    float* coefs = smem + 12256;    // [32]

    size_t bch = (size_t)(c * NH + h);
    size_t rowbase = (size_t)(c * T_);
    if (tid < 256) {
        acs_s[tid] = acs[bch * T_ + tid];
        dts[tid]   = dt_t[bch * T_ + tid];
    }

    // prefetch regs: 1 float4 each of B, C, x per thread (32x64 each)
    float4 pB, pC, pX;
    int rBC = tid >> 4, cBC = (tid & 15) * 4;
    auto issue = [&](int s) {
        const float* base = xbc + (rowbase + s * 32) * CONVD;
        pB = *(const float4*)(base + (size_t)rBC * CONVD + DI + cBC);
        pC = *(const float4*)(base + (size_t)rBC * CONVD + DI + NS + cBC);
        pX = *(const float4*)(base + (size_t)rBC * CONVD + h * HD + pbase + cBC);
    };
    issue(0);

    // H init from prev: pp = tid>>3 (0..63), n8 = (tid&7)*8
    int pp = tid >> 3, n8 = (tid & 7) * 8;
    {
        const float* src = prev + bch * (HD * NS) + (size_t)(pbase + pp) * NS + n8;
        #pragma unroll
        for (int j4 = 0; j4 < 2; j4++) {
            float4 v = *(const float4*)(src + j4 * 4);
            H[pp*65 + n8 + j4*4 + 0] = v.x;
            H[pp*65 + n8 + j4*4 + 1] = v.y;
            H[pp*65 + n8 + j4*4 + 2] = v.z;
            H[pp*65 + n8 + j4*4 + 3] = v.w;
        }
    }
    __syncthreads();

    float Dh = D_skip[h];
    int q2 = tid & 15;             // P3: q in {q2, q2+16}
    int p2 = (tid >> 4) * 2;       // P3: p = p2, p2+1 (local)
    int kq = tid >> 4;             // P2: q row (0..31)
    int kk0 = tid & 15;            // P2: k in {kk0, kk0+16}

    for (int s = 0; s < 8; s++) {
        int b32 = s * 32;
        float base = (s == 0) ? 0.f : acs_s[b32 - 1];
        float aL = acs_s[b32 + 31];

        // ---- P1: prefetched regs -> LDS
        *(float4*)&Bsh[rBC * 68 + cBC] = pB;
        *(float4*)&Cs [rBC * 68 + cBC] = pC;
        *(float4*)&xs [rBC * 68 + cBC] = pX;
        if (tid < 32)
            coefs[tid] = dts[b32 + tid] * expf(aL - acs_s[b32 + tid]);
        __syncthreads();

        if (s < 7) issue(s + 1);   // next sub-chunk, hidden under P2/P3
        // z-gate prefetch: 2 rows x 2 cols
        float2 pZ0 = *(const float2*)(zy + (rowbase + b32 + q2) * DPROJ + h * HD + pbase + p2);
        float2 pZ1 = *(const float2*)(zy + (rowbase + b32 + q2 + 16) * DPROJ + h * HD + pbase + p2);

        // ---- P2: S[kq][k] = (C·B)·exp(acs[q]-acs[k])·dt[k], q>=k
        {
            float sv0 = 0.f, sv1 = 0.f;
            for (int n = 0; n < NS; n++) {
                float cq = Cs[kq * 68 + n];
                sv0 = fmaf(cq, Bsh[kk0 * 68 + n], sv0);
                sv1 = fmaf(cq, Bsh[(kk0 + 16) * 68 + n], sv1);
            }
            float v0 = 0.f, v1 = 0.f;
            if (kq >= kk0)
                v0 = sv0 * expf(acs_s[b32+kq] - acs_s[b32+kk0]) * dts[b32+kk0];
            if (kq >= kk0+16)
                v1 = sv1 * expf(acs_s[b32+kq] - acs_s[b32+kk0+16]) * dts[b32+kk0+16];
            Ss[kq * 33 + kk0]      = v0;
            Ss[kq * 33 + kk0 + 16] = v1;
        }
        __syncthreads();

        // ---- P3: Y[q][p] = S·x + eq·(C·H) + D·x, gate, split-store (2q x 2p per thread)
        {
            float a00=0.f,a01=0.f,a10=0.f,a11=0.f;
            for (int kk = 0; kk < 32; kk++) {
                float s0 = Ss[q2 * 33 + kk];
                float s1 = Ss[(q2+16) * 33 + kk];
                float x0 = xs[kk*68 + p2 + 0];
                float x1 = xs[kk*68 + p2 + 1];
                a00 = fmaf(s0,x0,a00); a01 = fmaf(s0,x1,a01);
                a10 = fmaf(s1,x0,a10); a11 = fmaf(s1,x1,a11);
            }
            float eq0 = expf(acs_s[b32 + q2] - base);
            float eq1 = expf(acs_s[b32 + q2 + 16] - base);
            for (int n = 0; n < NS; n++) {
                float c0 = Cs[q2*68 + n] * eq0;
                float c1 = Cs[(q2+16)*68 + n] * eq1;
                float h0 = H[(p2+0)*65 + n];
                float h1 = H[(p2+1)*65 + n];
                a00 = fmaf(c0,h0,a00); a01 = fmaf(c0,h1,a01);
                a10 = fmaf(c1,h0,a10); a11 = fmaf(c1,h1,a11);
            }
            float y00 = (a00 + Dh * xs[q2*68 + p2+0]) * (pZ0.x / (1.f + expf(-pZ0.x)));
            float y01 = (a01 + Dh * xs[q2*68 + p2+1]) * (pZ0.y / (1.f + expf(-pZ0.y)));
            float y10 = (a10 + Dh * xs[(q2+16)*68 + p2+0]) * (pZ1.x / (1.f + expf(-pZ1.x)));
            float y11 = (a11 + Dh * xs[(q2+16)*68 + p2+1]) * (pZ1.y / (1.f + expf(-pZ1.y)));
            unsigned short* yb0 = (unsigned short*)(zy + (rowbase + b32 + q2) * DPROJ + DI);
            unsigned short* yb1 = (unsigned short*)(zy + (rowbase + b32 + q2 + 16) * DPROJ + DI);
            ushort2 h2v, l2v;
            bsplit(y00, h2v.x, l2v.x); bsplit(y01, h2v.y, l2v.y);
            *(ushort2*)(yb0 + h * HD + pbase + p2)        = h2v;
            *(ushort2*)(yb0 + 2048 + h * HD + pbase + p2) = l2v;
            bsplit(y10, h2v.x, l2v.x); bsplit(y11, h2v.y, l2v.y);
            *(ushort2*)(yb1 + h * HD + pbase + p2)        = h2v;
            *(ushort2*)(yb1 + 2048 + h * HD + pbase + p2) = l2v;
        }
        __syncthreads();   // all H reads done before update

        // ---- P4: H[pp][n8..n8+7] <- decay·H + B^T(coef·x)
        {
            float decay = expf(aL - base);
            float hreg[8];
            #pragma unroll
            for (int j = 0; j < 8; j++)
                hreg[j] = H[pp*65 + n8 + j] * decay;
            for (int t = 0; t < 32; t++) {
                float xa = xs[t*68 + pp] * coefs[t];
                #pragma unroll
                for (int j = 0; j < 8; j++)
                    hreg[j] = fmaf(xa, Bsh[t*68 + n8 + j], hreg[j]);
            }
            #pragma unroll
            for (int j = 0; j < 8; j++)
                H[pp*65 + n8 + j] = hreg[j];
        }
        __syncthreads();
    }
}

extern "C" void kernel_launch(void* const* d_in, const int* in_sizes, int n_in,
                              void* d_out, int out_size, void* d_ws, size_t ws_size,
                              hipStream_t stream)
{
    const float* x       = (const float*)d_in[0];
    const float* W_in    = (const float*)d_in[1];
    const float* conv_w  = (const float*)d_in[2];
    const float* conv_b  = (const float*)d_in[3];
    const float* A_log   = (const float*)d_in[4];
    const float* dt_bias = (const float*)d_in[5];
    const float* D_skip  = (const float*)d_in[6];
    const float* W_out   = (const float*)d_in[7];
    float* out = (float*)d_out;

    // workspace (~136 MB)
    float* proj   = (float*)d_ws;                          // L_*DPROJ
    float* xbc    = proj   + (size_t)L_ * DPROJ;           // L_*CONVD (also hosts XH/XL)
    float* dt_t   = xbc    + (size_t)L_ * CONVD;           // NC*NH*T_
    float* acs    = dt_t   + (size_t)NC * NH * T_;
    float* states = acs    + (size_t)NC * NH * T_;         // NC*NH*HD*NS
    unsigned short* WinH  = (unsigned short*)(states + (size_t)NC * NH * HD * NS);
    unsigned short* WinL  = WinH  + (size_t)NPADIN * DM;
    unsigned short* WoutH = WinL  + (size_t)NPADIN * DM;
    unsigned short* WoutL = WoutH + (size_t)DM * DI;
    unsigned short* XH = (unsigned short*)xbc;             // transient, dead before conv_silu
    unsigned short* XL = XH + (size_t)L_ * DM;
    unsigned short* projU = (unsigned short*)proj;

    dim3 blk(256);
    {   // one-time weight splits (W_in padded to NPADIN rows with zeros)
        int s4in = (DPROJ * DM) / 4, d4in = (NPADIN * DM) / 4;
        split_pad<<<dim3((d4in + 255) / 256), blk, 0, stream>>>(W_in, WinH, WinL, s4in, d4in);
        int n4out = (DM * DI) / 4;
        split_pad<<<dim3((n4out + 255) / 256), blk, 0, stream>>>(W_out, WoutH, WoutL, n4out, n4out);
    }

    for (int b = 0; b < B_; b++) {
        const float* xb = x + (size_t)b * L_ * DM;
        float* outb = out + (size_t)b * L_ * DM;
        int x4 = (L_ * DM) / 4;
        split_pad<<<dim3((x4 + 255) / 256), blk, 0, stream>>>(xb, XH, XL, x4, x4);
        mfma_gemm_lds<<<dim3((NPADIN / 128) * (L_ / 128)), blk, 0, stream>>>(
            XH, XL, (long)DM, WinH, WinL, proj, DPROJ, DM, DPROJ, L_ / 128);
        conv_silu<<<dim3((unsigned)(((size_t)L_ * CONVD + 255) / 256)), blk, 0, stream>>>(
            proj, conv_w, conv_b, xbc);
        dt_scan<<<dim3(NC * NH), blk, 0, stream>>>(proj, A_log, dt_bias, dt_t, acs);
        chunk_states<<<dim3(NC * NH), blk, 0, stream>>>(xbc, dt_t, acs, states);
        prev_rec<<<dim3(NH * 4), blk, 0, stream>>>(states, acs);
        y_chunk<<<dim3(NC * NH * 2), dim3(512), 0, stream>>>(xbc, dt_t, acs, states, D_skip, proj);
        // out-proj: A = split Y inside proj rows (hi at +DI*2 ushorts, lo at +DI*2+2048)
        mfma_gemm_lds<<<dim3((DM / 128) * (L_ / 128)), blk, 0, stream>>>(
            projU + (size_t)DI * 2, projU + (size_t)DI * 2 + 2048, (long)(DPROJ * 2),
            WoutH, WoutL, outb, DM, DI, DM, L_ / 128);
    }
}

// Round 13
// 839.553 us; speedup vs baseline: 1.3801x; 1.3801x over previous
//
#include <hip/hip_runtime.h>

#define B_     2
#define L_     4096
#define DM     1024
#define DI     2048
#define NH     16
#define HD     128
#define NS     64      // D_STATE
#define T_     256     // CHUNK
#define NC     16      // L_/T_
#define CONVD  2176    // DI + 2*NS
#define DPROJ  4240    // DI + CONVD + NH
#define NPADIN 4352    // 34*128, padded W_in rows

typedef __attribute__((ext_vector_type(8))) short bf16x8;
typedef __attribute__((ext_vector_type(4))) float f32x4;

// split fp32 -> bf16 hi (RNE) + bf16 lo (truncated residual)
__device__ __forceinline__ void bsplit(float x, unsigned short& h, unsigned short& l) {
    unsigned u = __float_as_uint(x);
    unsigned t = u + 0x7FFFu + ((u >> 16) & 1u);
    h = (unsigned short)(t >> 16);
    float lo = x - __uint_as_float(t & 0xFFFF0000u);
    l = (unsigned short)(__float_as_uint(lo) >> 16);
}

// ---------------- split fp32 matrix -> bf16 hi/lo, zero-padding tail rows ----------------
__global__ __launch_bounds__(256) void split_pad(
    const float* __restrict__ W, unsigned short* __restrict__ Wh,
    unsigned short* __restrict__ Wl, int srcN4, int dstN4)
{
    int i = blockIdx.x * 256 + threadIdx.x;
    if (i >= dstN4) return;
    ushort4 h = {0,0,0,0}, l = {0,0,0,0};
    if (i < srcN4) {
        float4 v = *(const float4*)(W + (size_t)i * 4);
        bsplit(v.x, h.x, l.x); bsplit(v.y, h.y, l.y);
        bsplit(v.z, h.z, l.z); bsplit(v.w, h.w, l.w);
    }
    *(ushort4*)(Wh + (size_t)i * 4) = h;
    *(ushort4*)(Wl + (size_t)i * 4) = l;
}

// ---------------- LDS-staged bf16x3 GEMM, pre-split A and W (r10 measured-good, exact) ----------------
__global__ __launch_bounds__(256, 2) void mfma_gemm_lds(
    const unsigned short* __restrict__ Ah, const unsigned short* __restrict__ Al,
    long arow, const unsigned short* __restrict__ Wh, const unsigned short* __restrict__ Wl,
    float* __restrict__ C, int N, int K, int ldc, int nyt)
{
    __shared__ unsigned short AhL[128 * 40];
    __shared__ unsigned short AlL[128 * 40];
    __shared__ unsigned short BhL[128 * 40];
    __shared__ unsigned short BlL[128 * 40];

    // XCD-chunked column-major tiling
    int NB = gridDim.x;
    int bid = blockIdx.x;
    int t = (bid & 7) * (NB >> 3) + (bid >> 3);
    int xt = t / nyt, yt = t % nyt;
    int tid = threadIdx.x;
    int lane = tid & 63, w = tid >> 6;
    int m0 = yt * 128, n0 = xt * 128;
    int mblk = (w >> 1) * 64, nblk = (w & 1) * 64;
    int fr = lane & 15;
    int fk = (lane >> 4) * 8;

    int sr0 = tid >> 2, sc0 = (tid & 3) * 8;
    int sr1 = (tid + 256) >> 2, sc1 = ((tid + 256) & 3) * 8;

    f32x4 acc[4][4];
    #pragma unroll
    for (int i = 0; i < 4; i++)
        #pragma unroll
        for (int j = 0; j < 4; j++) acc[i][j] = (f32x4){0.f, 0.f, 0.f, 0.f};

    int nk = K >> 5;
    for (int ks = 0; ks < nk; ks++) {
        int k0 = ks << 5;
        __syncthreads();
        {
            size_t a0 = (size_t)(m0 + sr0) * arow + k0 + sc0;
            size_t a1 = (size_t)(m0 + sr1) * arow + k0 + sc1;
            size_t b0 = (size_t)(n0 + sr0) * K + k0 + sc0;
            size_t b1 = (size_t)(n0 + sr1) * K + k0 + sc1;
            *(uint4*)&AhL[sr0 * 40 + sc0] = *(const uint4*)(Ah + a0);
            *(uint4*)&AhL[sr1 * 40 + sc1] = *(const uint4*)(Ah + a1);
            *(uint4*)&AlL[sr0 * 40 + sc0] = *(const uint4*)(Al + a0);
            *(uint4*)&AlL[sr1 * 40 + sc1] = *(const uint4*)(Al + a1);
            *(uint4*)&BhL[sr0 * 40 + sc0] = *(const uint4*)(Wh + b0);
            *(uint4*)&BhL[sr1 * 40 + sc1] = *(const uint4*)(Wh + b1);
            *(uint4*)&BlL[sr0 * 40 + sc0] = *(const uint4*)(Wl + b0);
            *(uint4*)&BlL[sr1 * 40 + sc1] = *(const uint4*)(Wl + b1);
        }
        __syncthreads();

        bf16x8 ah[4], al[4], bh[4], bl[4];
        #pragma unroll
        for (int tt = 0; tt < 4; tt++) {
            ah[tt] = *(const bf16x8*)&AhL[(mblk + tt*16 + fr) * 40 + fk];
            al[tt] = *(const bf16x8*)&AlL[(mblk + tt*16 + fr) * 40 + fk];
            bh[tt] = *(const bf16x8*)&BhL[(nblk + tt*16 + fr) * 40 + fk];
            bl[tt] = *(const bf16x8*)&BlL[(nblk + tt*16 + fr) * 40 + fk];
        }
        #pragma unroll
        for (int mt = 0; mt < 4; mt++)
            #pragma unroll
            for (int nt = 0; nt < 4; nt++) {
                f32x4 a = acc[mt][nt];
                a = __builtin_amdgcn_mfma_f32_16x16x32_bf16(al[mt], bh[nt], a, 0, 0, 0);
                a = __builtin_amdgcn_mfma_f32_16x16x32_bf16(ah[mt], bl[nt], a, 0, 0, 0);
                a = __builtin_amdgcn_mfma_f32_16x16x32_bf16(ah[mt], bh[nt], a, 0, 0, 0);
                acc[mt][nt] = a;
            }
    }

    int crow = (lane >> 4) * 4;
    #pragma unroll
    for (int mt = 0; mt < 4; mt++) {
        int rbase = m0 + mblk + mt*16 + crow;
        #pragma unroll
        for (int nt = 0; nt < 4; nt++) {
            int col = n0 + nblk + nt*16 + fr;
            if (col < N) {
                #pragma unroll
                for (int i = 0; i < 4; i++)
                    C[(size_t)(rbase + i) * ldc + col] = acc[mt][nt][i];
            }
        }
    }
}

// ---------------- depthwise causal conv (width 4) + bias + silu; 4 channels/thread ----------------
__global__ __launch_bounds__(256) void conv_silu(
    const float* __restrict__ proj, const float* __restrict__ w,
    const float* __restrict__ bias, float* __restrict__ xbc)
{
    size_t idx = (size_t)blockIdx.x * 256 + threadIdx.x;
    if (idx >= (size_t)L_ * (CONVD / 4)) return;
    int c4 = (int)(idx % (CONVD / 4)) * 4;
    int l  = (int)(idx / (CONVD / 4));
    float4 acc = *(const float4*)(bias + c4);
    const float* wr = w + c4 * 4;    // 16 contiguous floats: w[c4+k][j], k=0..3
    #pragma unroll
    for (int j = 0; j < 4; j++) {
        int ll = l - 3 + j;
        if (ll >= 0) {
            float4 pv = *(const float4*)(proj + (size_t)ll * DPROJ + DI + c4);
            acc.x = fmaf(pv.x, wr[0*4 + j], acc.x);
            acc.y = fmaf(pv.y, wr[1*4 + j], acc.y);
            acc.z = fmaf(pv.z, wr[2*4 + j], acc.z);
            acc.w = fmaf(pv.w, wr[3*4 + j], acc.w);
        }
    }
    acc.x = acc.x / (1.f + expf(-acc.x));
    acc.y = acc.y / (1.f + expf(-acc.y));
    acc.z = acc.z / (1.f + expf(-acc.z));
    acc.w = acc.w / (1.f + expf(-acc.w));
    *(float4*)(xbc + (size_t)l * CONVD + c4) = acc;
}

// ---------------- dt = softplus(dt_raw + bias); acs = cumsum(dt*A) within 256-chunk ----------------
__global__ __launch_bounds__(256) void dt_scan(
    const float* __restrict__ proj, const float* __restrict__ A_log,
    const float* __restrict__ dt_bias, float* __restrict__ dt_t, float* __restrict__ acs)
{
    int blk = blockIdx.x;            // c*NH + h
    int h = blk % NH;
    int c = blk / NH;
    int t = threadIdx.x;
    size_t row = (size_t)(c * T_ + t);
    float raw = proj[row * DPROJ + DI + CONVD + h] + dt_bias[h];
    float dtv = (raw > 20.f) ? raw : log1pf(expf(raw));
    float Ah = -expf(A_log[h]);
    __shared__ float buf[T_];
    buf[t] = dtv * Ah;
    __syncthreads();
    for (int off = 1; off < T_; off <<= 1) {
        float add = (t >= off) ? buf[t - off] : 0.f;
        __syncthreads();
        buf[t] += add;
        __syncthreads();
    }
    size_t o = (size_t)blk * T_ + t;
    dt_t[o] = dtv;
    acs[o]  = buf[t];
}

// ---------------- per-256-chunk states[p][n] = sum_t x[t,p]*B[t,n]*exp(acs_last-acs[t])*dt[t] ----------------
__global__ __launch_bounds__(256) void chunk_states(
    const float* __restrict__ xbc, const float* __restrict__ dt_t,
    const float* __restrict__ acs, float* __restrict__ states)
{
    int bid = blockIdx.x;            // XCD swizzle (grid 256)
    int blk = (bid & 7) * 32 + (bid >> 3);
    int h = blk % NH;
    int c = blk / NH;
    int tid = threadIdx.x;
    __shared__ float coef[T_];
    __shared__ __align__(16) float xs[32][HD];
    __shared__ float Bs[32][NS + 1];
    {
        size_t o = (size_t)blk * T_;
        float last = acs[o + T_ - 1];
        coef[tid] = expf(last - acs[o + tid]) * dt_t[o + tid];
    }
    __syncthreads();
    int tx = tid % 16;
    int ty = tid / 16;
    float acc[8][4];
    #pragma unroll
    for (int i = 0; i < 8; i++)
        #pragma unroll
        for (int j = 0; j < 4; j++) acc[i][j] = 0.f;
    size_t rowbase = (size_t)(c * T_);
    for (int t0 = 0; t0 < T_; t0 += 32) {
        #pragma unroll
        for (int i = 0; i < 4; i++) {
            int idx = tid + 256 * i;
            int r = idx >> 5, cv = idx & 31;
            float4 v = *(const float4*)(xbc + (rowbase + t0 + r) * CONVD + h * HD + cv * 4);
            *(float4*)&xs[r][cv * 4] = v;
        }
        #pragma unroll
        for (int i = 0; i < 2; i++) {
            int idx = tid + 256 * i;
            int r = idx >> 4, cv = idx & 15;
            float4 v = *(const float4*)(xbc + (rowbase + t0 + r) * CONVD + DI + cv * 4);
            float wc = coef[t0 + r];
            Bs[r][cv*4+0] = v.x * wc; Bs[r][cv*4+1] = v.y * wc;
            Bs[r][cv*4+2] = v.z * wc; Bs[r][cv*4+3] = v.w * wc;
        }
        __syncthreads();
        #pragma unroll
        for (int tt = 0; tt < 32; tt++) {
            float xv[8], bv[4];
            #pragma unroll
            for (int i = 0; i < 8; i++) xv[i] = xs[tt][ty*8+i];
            #pragma unroll
            for (int j = 0; j < 4; j++) bv[j] = Bs[tt][tx*4+j];
            #pragma unroll
            for (int i = 0; i < 8; i++)
                #pragma unroll
                for (int j = 0; j < 4; j++)
                    acc[i][j] = fmaf(xv[i], bv[j], acc[i][j]);
        }
        __syncthreads();
    }
    size_t base = (size_t)blk * HD * NS;
    #pragma unroll
    for (int i = 0; i < 8; i++)
        #pragma unroll
        for (int j = 0; j < 4; j++)
            states[base + (size_t)(ty*8+i) * NS + tx*4+j] = acc[i][j];
}

// ---------------- in-place inter-chunk recurrence: states[c] <- prev[c] ----------------
__global__ __launch_bounds__(256) void prev_rec(
    float* __restrict__ states, const float* __restrict__ acs)
{
    int blk = blockIdx.x;          // h*4 + pq
    int pq = blk % 4;
    int h = blk / 4;
    int tid = threadIdx.x;
    int s = tid * 8;
    int p = pq * 32 + s / NS;
    int n0 = s % NS;
    float run[8];
    #pragma unroll
    for (int j = 0; j < 8; j++) run[j] = 0.f;
    for (int c = 0; c < NC; c++) {
        size_t ch = (size_t)(c * NH + h);
        size_t off = ch * HD * NS + (size_t)p * NS + n0;
        float sv[8];
        #pragma unroll
        for (int j = 0; j < 8; j++) sv[j] = states[off + j];
        #pragma unroll
        for (int j = 0; j < 8; j++) states[off + j] = run[j];
        float f = expf(acs[ch * T_ + T_ - 1]);
        #pragma unroll
        for (int j = 0; j < 8; j++) run[j] = sv[j] + f * run[j];
    }
}

// ---------------- fused Y per (chunk,head); gated output written as SPLIT bf16 (r10 exact) ----------------
__global__ __launch_bounds__(512, 2) void y_chunk(
    const float* __restrict__ xbc, const float* __restrict__ dt_t,
    const float* __restrict__ acs, const float* __restrict__ prev,
    const float* __restrict__ D_skip, float* zy /* = proj */)
{
    int bid = blockIdx.x;
    int l = (bid & 7) * 32 + (bid >> 3);   // XCD swizzle
    int h = l & 15;
    int c = l >> 4;
    int tid = threadIdx.x;

    __shared__ __align__(16) float smem[18496];
    float* H     = smem;            // [128][65]
    float* Cs    = smem + 8320;     // [32][68]
    float* Bsh   = smem + 10496;    // [32][68]
    float* xs    = smem + 12672;    // [32][132]
    float* Ss    = smem + 16896;    // [32][33]
    float* acs_s = smem + 17952;    // [256]
    float* dts   = smem + 18208;    // [256]
    float* coefs = smem + 18464;    // [32]

    size_t bch = (size_t)(c * NH + h);
    size_t rowbase = (size_t)(c * T_);
    if (tid < 256) {
        acs_s[tid] = acs[bch * T_ + tid];
        dts[tid]   = dt_t[bch * T_ + tid];
    }

    float4 pB, pC, pX0, pX1;
    int rBC = tid >> 4, cBC = (tid & 15) * 4;
    int rX0 = tid >> 5, cX0 = (tid & 31) * 4;
    int rX1 = (tid + 512) >> 5;
    auto issue = [&](int s) {
        const float* base = xbc + (rowbase + s * 32) * CONVD;
        pB  = *(const float4*)(base + (size_t)rBC * CONVD + DI + cBC);
        pC  = *(const float4*)(base + (size_t)rBC * CONVD + DI + NS + cBC);
        pX0 = *(const float4*)(base + (size_t)rX0 * CONVD + h * HD + cX0);
        pX1 = *(const float4*)(base + (size_t)rX1 * CONVD + h * HD + cX0);
    };
    issue(0);

    int pp = tid >> 2, n0 = (tid & 3) * 16;
    {
        const float* src = prev + bch * (HD * NS) + (size_t)pp * NS + n0;
        #pragma unroll
        for (int j4 = 0; j4 < 4; j4++) {
            float4 v = *(const float4*)(src + j4 * 4);
            H[pp*65 + n0 + j4*4 + 0] = v.x;
            H[pp*65 + n0 + j4*4 + 1] = v.y;
            H[pp*65 + n0 + j4*4 + 2] = v.z;
            H[pp*65 + n0 + j4*4 + 3] = v.w;
        }
    }
    __syncthreads();

    float Dh = D_skip[h];
    int q2 = tid & 15;
    int p4 = (tid >> 4) * 4;
    int kq = tid >> 4;
    int kk0 = tid & 15;

    for (int s = 0; s < 8; s++) {
        int b32 = s * 32;
        float base = (s == 0) ? 0.f : acs_s[b32 - 1];
        float aL = acs_s[b32 + 31];

        *(float4*)&Bsh[rBC * 68 + cBC]  = pB;
        *(float4*)&Cs [rBC * 68 + cBC]  = pC;
        *(float4*)&xs [rX0 * 132 + cX0] = pX0;
        *(float4*)&xs [rX1 * 132 + cX0] = pX1;
        if (tid < 32)
            coefs[tid] = dts[b32 + tid] * expf(aL - acs_s[b32 + tid]);
        __syncthreads();

        if (s < 7) issue(s + 1);
        float4 pZ0 = *(const float4*)(zy + (rowbase + b32 + q2) * DPROJ + h * HD + p4);
        float4 pZ1 = *(const float4*)(zy + (rowbase + b32 + q2 + 16) * DPROJ + h * HD + p4);

        {
            float sv0 = 0.f, sv1 = 0.f;
            for (int n = 0; n < NS; n++) {
                float cq = Cs[kq * 68 + n];
                sv0 = fmaf(cq, Bsh[kk0 * 68 + n], sv0);
                sv1 = fmaf(cq, Bsh[(kk0 + 16) * 68 + n], sv1);
            }
            float v0 = 0.f, v1 = 0.f;
            if (kq >= kk0)
                v0 = sv0 * expf(acs_s[b32+kq] - acs_s[b32+kk0]) * dts[b32+kk0];
            if (kq >= kk0+16)
                v1 = sv1 * expf(acs_s[b32+kq] - acs_s[b32+kk0+16]) * dts[b32+kk0+16];
            Ss[kq * 33 + kk0]      = v0;
            Ss[kq * 33 + kk0 + 16] = v1;
        }
        __syncthreads();

        {
            float a00=0.f,a01=0.f,a02=0.f,a03=0.f;
            float a10=0.f,a11=0.f,a12=0.f,a13=0.f;
            for (int kk = 0; kk < 32; kk++) {
                float s0 = Ss[q2 * 33 + kk];
                float s1 = Ss[(q2+16) * 33 + kk];
                float x0 = xs[kk*132 + p4 + 0];
                float x1 = xs[kk*132 + p4 + 1];
                float x2 = xs[kk*132 + p4 + 2];
                float x3 = xs[kk*132 + p4 + 3];
                a00 = fmaf(s0,x0,a00); a01 = fmaf(s0,x1,a01);
                a02 = fmaf(s0,x2,a02); a03 = fmaf(s0,x3,a03);
                a10 = fmaf(s1,x0,a10); a11 = fmaf(s1,x1,a11);
                a12 = fmaf(s1,x2,a12); a13 = fmaf(s1,x3,a13);
            }
            float eq0 = expf(acs_s[b32 + q2] - base);
            float eq1 = expf(acs_s[b32 + q2 + 16] - base);
            for (int n = 0; n < NS; n++) {
                float c0 = Cs[q2*68 + n] * eq0;
                float c1 = Cs[(q2+16)*68 + n] * eq1;
                float h0 = H[(p4+0)*65 + n];
                float h1 = H[(p4+1)*65 + n];
                float h2 = H[(p4+2)*65 + n];
                float h3 = H[(p4+3)*65 + n];
                a00 = fmaf(c0,h0,a00); a01 = fmaf(c0,h1,a01);
                a02 = fmaf(c0,h2,a02); a03 = fmaf(c0,h3,a03);
                a10 = fmaf(c1,h0,a10); a11 = fmaf(c1,h1,a11);
                a12 = fmaf(c1,h2,a12); a13 = fmaf(c1,h3,a13);
            }
            float y00 = (a00 + Dh * xs[q2*132 + p4+0]) * (pZ0.x / (1.f + expf(-pZ0.x)));
            float y01 = (a01 + Dh * xs[q2*132 + p4+1]) * (pZ0.y / (1.f + expf(-pZ0.y)));
            float y02 = (a02 + Dh * xs[q2*132 + p4+2]) * (pZ0.z / (1.f + expf(-pZ0.z)));
            float y03 = (a03 + Dh * xs[q2*132 + p4+3]) * (pZ0.w / (1.f + expf(-pZ0.w)));
            float y10 = (a10 + Dh * xs[(q2+16)*132 + p4+0]) * (pZ1.x / (1.f + expf(-pZ1.x)));
            float y11 = (a11 + Dh * xs[(q2+16)*132 + p4+1]) * (pZ1.y / (1.f + expf(-pZ1.y)));
            float y12 = (a12 + Dh * xs[(q2+16)*132 + p4+2]) * (pZ1.z / (1.f + expf(-pZ1.z)));
            float y13 = (a13 + Dh * xs[(q2+16)*132 + p4+3]) * (pZ1.w / (1.f + expf(-pZ1.w)));
            unsigned short* yb0 = (unsigned short*)(zy + (rowbase + b32 + q2) * DPROJ + DI);
            unsigned short* yb1 = (unsigned short*)(zy + (rowbase + b32 + q2 + 16) * DPROJ + DI);
            ushort4 h4, l4;
            bsplit(y00, h4.x, l4.x); bsplit(y01, h4.y, l4.y);
            bsplit(y02, h4.z, l4.z); bsplit(y03, h4.w, l4.w);
            *(ushort4*)(yb0 + h * HD + p4)        = h4;
            *(ushort4*)(yb0 + 2048 + h * HD + p4) = l4;
            bsplit(y10, h4.x, l4.x); bsplit(y11, h4.y, l4.y);
            bsplit(y12, h4.z, l4.z); bsplit(y13, h4.w, l4.w);
            *(ushort4*)(yb1 + h * HD + p4)        = h4;
            *(ushort4*)(yb1 + 2048 + h * HD + p4) = l4;
        }
        __syncthreads();

        {
            float decay = expf(aL - base);
            float hreg[16];
            #pragma unroll
            for (int j = 0; j < 16; j++)
                hreg[j] = H[pp*65 + n0 + j] * decay;
            for (int t = 0; t < 32; t++) {
                float xa = xs[t*132 + pp] * coefs[t];
                #pragma unroll
                for (int j = 0; j < 16; j++)
                    hreg[j] = fmaf(xa, Bsh[t*68 + n0 + j], hreg[j]);
            }
            #pragma unroll
            for (int j = 0; j < 16; j++)
                H[pp*65 + n0 + j] = hreg[j];
        }
        __syncthreads();
    }
}

extern "C" void kernel_launch(void* const* d_in, const int* in_sizes, int n_in,
                              void* d_out, int out_size, void* d_ws, size_t ws_size,
                              hipStream_t stream)
{
    const float* x       = (const float*)d_in[0];
    const float* W_in    = (const float*)d_in[1];
    const float* conv_w  = (const float*)d_in[2];
    const float* conv_b  = (const float*)d_in[3];
    const float* A_log   = (const float*)d_in[4];
    const float* dt_bias = (const float*)d_in[5];
    const float* D_skip  = (const float*)d_in[6];
    const float* W_out   = (const float*)d_in[7];
    float* out = (float*)d_out;

    // workspace (~136 MB)
    float* proj   = (float*)d_ws;                          // L_*DPROJ
    float* xbc    = proj   + (size_t)L_ * DPROJ;           // L_*CONVD (also hosts XH/XL)
    float* dt_t   = xbc    + (size_t)L_ * CONVD;           // NC*NH*T_
    float* acs    = dt_t   + (size_t)NC * NH * T_;
    float* states = acs    + (size_t)NC * NH * T_;         // NC*NH*HD*NS
    unsigned short* WinH  = (unsigned short*)(states + (size_t)NC * NH * HD * NS);
    unsigned short* WinL  = WinH  + (size_t)NPADIN * DM;
    unsigned short* WoutH = WinL  + (size_t)NPADIN * DM;
    unsigned short* WoutL = WoutH + (size_t)DM * DI;
    unsigned short* XH = (unsigned short*)xbc;             // transient, dead before conv_silu
    unsigned short* XL = XH + (size_t)L_ * DM;
    unsigned short* projU = (unsigned short*)proj;

    dim3 blk(256);
    {   // one-time weight splits (W_in padded to NPADIN rows with zeros)
        int s4in = (DPROJ * DM) / 4, d4in = (NPADIN * DM) / 4;
        split_pad<<<dim3((d4in + 255) / 256), blk, 0, stream>>>(W_in, WinH, WinL, s4in, d4in);
        int n4out = (DM * DI) / 4;
        split_pad<<<dim3((n4out + 255) / 256), blk, 0, stream>>>(W_out, WoutH, WoutL, n4out, n4out);
    }

    for (int b = 0; b < B_; b++) {
        const float* xb = x + (size_t)b * L_ * DM;
        float* outb = out + (size_t)b * L_ * DM;
        int x4 = (L_ * DM) / 4;
        split_pad<<<dim3((x4 + 255) / 256), blk, 0, stream>>>(xb, XH, XL, x4, x4);
        mfma_gemm_lds<<<dim3((NPADIN / 128) * (L_ / 128)), blk, 0, stream>>>(
            XH, XL, (long)DM, WinH, WinL, proj, DPROJ, DM, DPROJ, L_ / 128);
        conv_silu<<<dim3((unsigned)(((size_t)L_ * (CONVD / 4) + 255) / 256)), blk, 0, stream>>>(
            proj, conv_w, conv_b, xbc);
        dt_scan<<<dim3(NC * NH), blk, 0, stream>>>(proj, A_log, dt_bias, dt_t, acs);
        chunk_states<<<dim3(NC * NH), blk, 0, stream>>>(xbc, dt_t, acs, states);
        prev_rec<<<dim3(NH * 4), blk, 0, stream>>>(states, acs);
        y_chunk<<<dim3(NC * NH), dim3(512), 0, stream>>>(xbc, dt_t, acs, states, D_skip, proj);
        // out-proj: A = split Y inside proj rows (hi at +DI*2 ushorts, lo at +DI*2+2048)
        mfma_gemm_lds<<<dim3((DM / 128) * (L_ / 128)), blk, 0, stream>>>(
            projU + (size_t)DI * 2, projU + (size_t)DI * 2 + 2048, (long)(DPROJ * 2),
            WoutH, WoutL, outb, DM, DI, DM, L_ / 128);
    }
}

// Round 14
// 767.383 us; speedup vs baseline: 1.5099x; 1.0940x over previous
//
#include <hip/hip_runtime.h>

#define B_     2
#define L_     4096
#define DM     1024
#define DI     2048
#define NH     16
#define HD     128
#define NS     64      // D_STATE
#define T_     256     // CHUNK
#define NC     16      // L_/T_
#define CONVD  2176    // DI + 2*NS
#define DPROJ  4240    // DI + CONVD + NH
#define NPADIN 4352    // 34*128, padded W_in rows

typedef __attribute__((ext_vector_type(8))) short bf16x8;
typedef __attribute__((ext_vector_type(4))) float f32x4;

// split fp32 -> bf16 hi (RNE) + bf16 lo (truncated residual)
__device__ __forceinline__ void bsplit(float x, unsigned short& h, unsigned short& l) {
    unsigned u = __float_as_uint(x);
    unsigned t = u + 0x7FFFu + ((u >> 16) & 1u);
    h = (unsigned short)(t >> 16);
    float lo = x - __uint_as_float(t & 0xFFFF0000u);
    l = (unsigned short)(__float_as_uint(lo) >> 16);
}

// async global->LDS 16B (DMA, no VGPR round trip). LDS dest must be wave-uniform
// base + lane*16 — guaranteed by chunk==tid linear mapping at the call sites.
__device__ __forceinline__ void glds16(const unsigned short* g, unsigned short* l) {
    __builtin_amdgcn_global_load_lds(
        (const __attribute__((address_space(1))) void*)g,
        (__attribute__((address_space(3))) void*)l, 16, 0, 0);
}

// ---------------- split fp32 matrix -> bf16 hi/lo, zero-padding tail rows ----------------
__global__ __launch_bounds__(256) void split_pad(
    const float* __restrict__ W, unsigned short* __restrict__ Wh,
    unsigned short* __restrict__ Wl, int srcN4, int dstN4)
{
    int i = blockIdx.x * 256 + threadIdx.x;
    if (i >= dstN4) return;
    ushort4 h = {0,0,0,0}, l = {0,0,0,0};
    if (i < srcN4) {
        float4 v = *(const float4*)(W + (size_t)i * 4);
        bsplit(v.x, h.x, l.x); bsplit(v.y, h.y, l.y);
        bsplit(v.z, h.z, l.z); bsplit(v.w, h.w, l.w);
    }
    *(ushort4*)(Wh + (size_t)i * 4) = h;
    *(ushort4*)(Wl + (size_t)i * 4) = l;
}

// ---------------- LDS-staged bf16x3 GEMM; staging via global_load_lds (m97 pattern) ----------------
// C[m,n] = sum_k A[m,k]*W[n,k]; 128x128 tile, BK=32, 4 waves (64x64 each),
// linear [128][32] ushort LDS (lane-linear DMA dest), 32KB LDS.
__global__ __launch_bounds__(256, 2) void mfma_gemm_lds(
    const unsigned short* __restrict__ Ah, const unsigned short* __restrict__ Al,
    long arow, const unsigned short* __restrict__ Wh, const unsigned short* __restrict__ Wl,
    float* __restrict__ C, int N, int K, int ldc, int nyt)
{
    __shared__ unsigned short AhL[128 * 32];
    __shared__ unsigned short AlL[128 * 32];
    __shared__ unsigned short BhL[128 * 32];
    __shared__ unsigned short BlL[128 * 32];

    // XCD-chunked column-major tiling
    int NB = gridDim.x;
    int bid = blockIdx.x;
    int t = (bid & 7) * (NB >> 3) + (bid >> 3);
    int xt = t / nyt, yt = t % nyt;
    int tid = threadIdx.x;
    int lane = tid & 63, w = tid >> 6;
    int m0 = yt * 128, n0 = xt * 128;
    int mblk = (w >> 1) * 64, nblk = (w & 1) * 64;
    int fr = lane & 15;
    int fk = (lane >> 4) * 8;

    // staging chunks (16B each): chunk0 = tid, chunk1 = tid+256; row = chunk>>2, kcol = (chunk&3)*8
    int r0 = tid >> 2,         kc0 = (tid & 3) * 8;
    int r1 = (tid + 256) >> 2, kc1 = ((tid + 256) & 3) * 8;
    int lo0 = tid * 8;           // ushort offset in LDS (= 16B * chunk)
    int lo1 = (tid + 256) * 8;

    f32x4 acc[4][4];
    #pragma unroll
    for (int i = 0; i < 4; i++)
        #pragma unroll
        for (int j = 0; j < 4; j++) acc[i][j] = (f32x4){0.f, 0.f, 0.f, 0.f};

    int nk = K >> 5;
    for (int ks = 0; ks < nk; ks++) {
        int k0 = ks << 5;
        __syncthreads();   // previous tile's frag reads done before DMA overwrites
        {
            size_t a0 = (size_t)(m0 + r0) * arow + k0 + kc0;
            size_t a1 = (size_t)(m0 + r1) * arow + k0 + kc1;
            size_t b0 = (size_t)(n0 + r0) * K + k0 + kc0;
            size_t b1 = (size_t)(n0 + r1) * K + k0 + kc1;
            glds16(Ah + a0, AhL + lo0);
            glds16(Ah + a1, AhL + lo1);
            glds16(Al + a0, AlL + lo0);
            glds16(Al + a1, AlL + lo1);
            glds16(Wh + b0, BhL + lo0);
            glds16(Wh + b1, BhL + lo1);
            glds16(Wl + b0, BlL + lo0);
            glds16(Wl + b1, BlL + lo1);
        }
        __syncthreads();   // barrier drains vmcnt -> DMA data visible

        bf16x8 ah[4], al[4], bh[4], bl[4];
        #pragma unroll
        for (int tt = 0; tt < 4; tt++) {
            int oa = (mblk + tt*16 + fr) * 32 + fk;
            int ob = (nblk + tt*16 + fr) * 32 + fk;
            ah[tt] = *(const bf16x8*)&AhL[oa];
            al[tt] = *(const bf16x8*)&AlL[oa];
            bh[tt] = *(const bf16x8*)&BhL[ob];
            bl[tt] = *(const bf16x8*)&BlL[ob];
        }
        #pragma unroll
        for (int mt = 0; mt < 4; mt++)
            #pragma unroll
            for (int nt = 0; nt < 4; nt++) {
                f32x4 a = acc[mt][nt];
                a = __builtin_amdgcn_mfma_f32_16x16x32_bf16(al[mt], bh[nt], a, 0, 0, 0);
                a = __builtin_amdgcn_mfma_f32_16x16x32_bf16(ah[mt], bl[nt], a, 0, 0, 0);
                a = __builtin_amdgcn_mfma_f32_16x16x32_bf16(ah[mt], bh[nt], a, 0, 0, 0);
                acc[mt][nt] = a;
            }
    }

    int crow = (lane >> 4) * 4;
    #pragma unroll
    for (int mt = 0; mt < 4; mt++) {
        int rbase = m0 + mblk + mt*16 + crow;
        #pragma unroll
        for (int nt = 0; nt < 4; nt++) {
            int col = n0 + nblk + nt*16 + fr;
            if (col < N) {
                #pragma unroll
                for (int i = 0; i < 4; i++)
                    C[(size_t)(rbase + i) * ldc + col] = acc[mt][nt][i];
            }
        }
    }
}

// ---------------- depthwise causal conv (width 4) + bias + silu; one batch (r10 exact) ----------------
__global__ void conv_silu(const float* __restrict__ proj, const float* __restrict__ w,
                          const float* __restrict__ bias, float* __restrict__ xbc)
{
    size_t idx = (size_t)blockIdx.x * 256 + threadIdx.x;
    if (idx >= (size_t)L_ * CONVD) return;
    int c = (int)(idx % CONVD);
    int l = (int)(idx / CONVD);
    float acc = bias[c];
    #pragma unroll
    for (int j = 0; j < 4; j++) {
        int ll = l - 3 + j;
        if (ll >= 0)
            acc = fmaf(proj[(size_t)ll * DPROJ + DI + c], w[c*4+j], acc);
    }
    acc = acc / (1.f + expf(-acc));   // silu
    xbc[(size_t)l * CONVD + c] = acc;
}

// ---------------- dt = softplus(dt_raw + bias); acs = cumsum(dt*A) within 256-chunk ----------------
__global__ __launch_bounds__(256) void dt_scan(
    const float* __restrict__ proj, const float* __restrict__ A_log,
    const float* __restrict__ dt_bias, float* __restrict__ dt_t, float* __restrict__ acs)
{
    int blk = blockIdx.x;            // c*NH + h
    int h = blk % NH;
    int c = blk / NH;
    int t = threadIdx.x;
    size_t row = (size_t)(c * T_ + t);
    float raw = proj[row * DPROJ + DI + CONVD + h] + dt_bias[h];
    float dtv = (raw > 20.f) ? raw : log1pf(expf(raw));
    float Ah = -expf(A_log[h]);
    __shared__ float buf[T_];
    buf[t] = dtv * Ah;
    __syncthreads();
    for (int off = 1; off < T_; off <<= 1) {
        float add = (t >= off) ? buf[t - off] : 0.f;
        __syncthreads();
        buf[t] += add;
        __syncthreads();
    }
    size_t o = (size_t)blk * T_ + t;
    dt_t[o] = dtv;
    acs[o]  = buf[t];
}

// ---------------- per-256-chunk states[p][n] = sum_t x[t,p]*B[t,n]*exp(acs_last-acs[t])*dt[t] ----------------
__global__ __launch_bounds__(256) void chunk_states(
    const float* __restrict__ xbc, const float* __restrict__ dt_t,
    const float* __restrict__ acs, float* __restrict__ states)
{
    int bid = blockIdx.x;            // XCD swizzle (grid 256)
    int blk = (bid & 7) * 32 + (bid >> 3);
    int h = blk % NH;
    int c = blk / NH;
    int tid = threadIdx.x;
    __shared__ float coef[T_];
    __shared__ __align__(16) float xs[32][HD];
    __shared__ float Bs[32][NS + 1];
    {
        size_t o = (size_t)blk * T_;
        float last = acs[o + T_ - 1];
        coef[tid] = expf(last - acs[o + tid]) * dt_t[o + tid];
    }
    __syncthreads();
    int tx = tid % 16;
    int ty = tid / 16;
    float acc[8][4];
    #pragma unroll
    for (int i = 0; i < 8; i++)
        #pragma unroll
        for (int j = 0; j < 4; j++) acc[i][j] = 0.f;
    size_t rowbase = (size_t)(c * T_);
    for (int t0 = 0; t0 < T_; t0 += 32) {
        #pragma unroll
        for (int i = 0; i < 4; i++) {
            int idx = tid + 256 * i;
            int r = idx >> 5, cv = idx & 31;
            float4 v = *(const float4*)(xbc + (rowbase + t0 + r) * CONVD + h * HD + cv * 4);
            *(float4*)&xs[r][cv * 4] = v;
        }
        #pragma unroll
        for (int i = 0; i < 2; i++) {
            int idx = tid + 256 * i;
            int r = idx >> 4, cv = idx & 15;
            float4 v = *(const float4*)(xbc + (rowbase + t0 + r) * CONVD + DI + cv * 4);
            float wc = coef[t0 + r];
            Bs[r][cv*4+0] = v.x * wc; Bs[r][cv*4+1] = v.y * wc;
            Bs[r][cv*4+2] = v.z * wc; Bs[r][cv*4+3] = v.w * wc;
        }
        __syncthreads();
        #pragma unroll
        for (int tt = 0; tt < 32; tt++) {
            float xv[8], bv[4];
            #pragma unroll
            for (int i = 0; i < 8; i++) xv[i] = xs[tt][ty*8+i];
            #pragma unroll
            for (int j = 0; j < 4; j++) bv[j] = Bs[tt][tx*4+j];
            #pragma unroll
            for (int i = 0; i < 8; i++)
                #pragma unroll
                for (int j = 0; j < 4; j++)
                    acc[i][j] = fmaf(xv[i], bv[j], acc[i][j]);
        }
        __syncthreads();
    }
    size_t base = (size_t)blk * HD * NS;
    #pragma unroll
    for (int i = 0; i < 8; i++)
        #pragma unroll
        for (int j = 0; j < 4; j++)
            states[base + (size_t)(ty*8+i) * NS + tx*4+j] = acc[i][j];
}

// ---------------- in-place inter-chunk recurrence: states[c] <- prev[c] ----------------
__global__ __launch_bounds__(256) void prev_rec(
    float* __restrict__ states, const float* __restrict__ acs)
{
    int blk = blockIdx.x;          // h*4 + pq
    int pq = blk % 4;
    int h = blk / 4;
    int tid = threadIdx.x;
    int s = tid * 8;
    int p = pq * 32 + s / NS;
    int n0 = s % NS;
    float run[8];
    #pragma unroll
    for (int j = 0; j < 8; j++) run[j] = 0.f;
    for (int c = 0; c < NC; c++) {
        size_t ch = (size_t)(c * NH + h);
        size_t off = ch * HD * NS + (size_t)p * NS + n0;
        float sv[8];
        #pragma unroll
        for (int j = 0; j < 8; j++) sv[j] = states[off + j];
        #pragma unroll
        for (int j = 0; j < 8; j++) states[off + j] = run[j];
        float f = expf(acs[ch * T_ + T_ - 1]);
        #pragma unroll
        for (int j = 0; j < 8; j++) run[j] = sv[j] + f * run[j];
    }
}

// ---------------- fused Y per (chunk,head); gated output written as SPLIT bf16 (r10 exact) ----------------
__global__ __launch_bounds__(512, 2) void y_chunk(
    const float* __restrict__ xbc, const float* __restrict__ dt_t,
    const float* __restrict__ acs, const float* __restrict__ prev,
    const float* __restrict__ D_skip, float* zy /* = proj */)
{
    int bid = blockIdx.x;
    int l = (bid & 7) * 32 + (bid >> 3);   // XCD swizzle
    int h = l & 15;
    int c = l >> 4;
    int tid = threadIdx.x;

    __shared__ __align__(16) float smem[18496];
    float* H     = smem;            // [128][65]
    float* Cs    = smem + 8320;     // [32][68]
    float* Bsh   = smem + 10496;    // [32][68]
    float* xs    = smem + 12672;    // [32][132]
    float* Ss    = smem + 16896;    // [32][33]
    float* acs_s = smem + 17952;    // [256]
    float* dts   = smem + 18208;    // [256]
    float* coefs = smem + 18464;    // [32]

    size_t bch = (size_t)(c * NH + h);
    size_t rowbase = (size_t)(c * T_);
    if (tid < 256) {
        acs_s[tid] = acs[bch * T_ + tid];
        dts[tid]   = dt_t[bch * T_ + tid];
    }

    float4 pB, pC, pX0, pX1;
    int rBC = tid >> 4, cBC = (tid & 15) * 4;
    int rX0 = tid >> 5, cX0 = (tid & 31) * 4;
    int rX1 = (tid + 512) >> 5;
    auto issue = [&](int s) {
        const float* base = xbc + (rowbase + s * 32) * CONVD;
        pB  = *(const float4*)(base + (size_t)rBC * CONVD + DI + cBC);
        pC  = *(const float4*)(base + (size_t)rBC * CONVD + DI + NS + cBC);
        pX0 = *(const float4*)(base + (size_t)rX0 * CONVD + h * HD + cX0);
        pX1 = *(const float4*)(base + (size_t)rX1 * CONVD + h * HD + cX0);
    };
    issue(0);

    int pp = tid >> 2, n0 = (tid & 3) * 16;
    {
        const float* src = prev + bch * (HD * NS) + (size_t)pp * NS + n0;
        #pragma unroll
        for (int j4 = 0; j4 < 4; j4++) {
            float4 v = *(const float4*)(src + j4 * 4);
            H[pp*65 + n0 + j4*4 + 0] = v.x;
            H[pp*65 + n0 + j4*4 + 1] = v.y;
            H[pp*65 + n0 + j4*4 + 2] = v.z;
            H[pp*65 + n0 + j4*4 + 3] = v.w;
        }
    }
    __syncthreads();

    float Dh = D_skip[h];
    int q2 = tid & 15;
    int p4 = (tid >> 4) * 4;
    int kq = tid >> 4;
    int kk0 = tid & 15;

    for (int s = 0; s < 8; s++) {
        int b32 = s * 32;
        float base = (s == 0) ? 0.f : acs_s[b32 - 1];
        float aL = acs_s[b32 + 31];

        *(float4*)&Bsh[rBC * 68 + cBC]  = pB;
        *(float4*)&Cs [rBC * 68 + cBC]  = pC;
        *(float4*)&xs [rX0 * 132 + cX0] = pX0;
        *(float4*)&xs [rX1 * 132 + cX0] = pX1;
        if (tid < 32)
            coefs[tid] = dts[b32 + tid] * expf(aL - acs_s[b32 + tid]);
        __syncthreads();

        if (s < 7) issue(s + 1);
        float4 pZ0 = *(const float4*)(zy + (rowbase + b32 + q2) * DPROJ + h * HD + p4);
        float4 pZ1 = *(const float4*)(zy + (rowbase + b32 + q2 + 16) * DPROJ + h * HD + p4);

        {
            float sv0 = 0.f, sv1 = 0.f;
            for (int n = 0; n < NS; n++) {
                float cq = Cs[kq * 68 + n];
                sv0 = fmaf(cq, Bsh[kk0 * 68 + n], sv0);
                sv1 = fmaf(cq, Bsh[(kk0 + 16) * 68 + n], sv1);
            }
            float v0 = 0.f, v1 = 0.f;
            if (kq >= kk0)
                v0 = sv0 * expf(acs_s[b32+kq] - acs_s[b32+kk0]) * dts[b32+kk0];
            if (kq >= kk0+16)
                v1 = sv1 * expf(acs_s[b32+kq] - acs_s[b32+kk0+16]) * dts[b32+kk0+16];
            Ss[kq * 33 + kk0]      = v0;
            Ss[kq * 33 + kk0 + 16] = v1;
        }
        __syncthreads();

        {
            float a00=0.f,a01=0.f,a02=0.f,a03=0.f;
            float a10=0.f,a11=0.f,a12=0.f,a13=0.f;
            for (int kk = 0; kk < 32; kk++) {
                float s0 = Ss[q2 * 33 + kk];
                float s1 = Ss[(q2+16) * 33 + kk];
                float x0 = xs[kk*132 + p4 + 0];
                float x1 = xs[kk*132 + p4 + 1];
                float x2 = xs[kk*132 + p4 + 2];
                float x3 = xs[kk*132 + p4 + 3];
                a00 = fmaf(s0,x0,a00); a01 = fmaf(s0,x1,a01);
                a02 = fmaf(s0,x2,a02); a03 = fmaf(s0,x3,a03);
                a10 = fmaf(s1,x0,a10); a11 = fmaf(s1,x1,a11);
                a12 = fmaf(s1,x2,a12); a13 = fmaf(s1,x3,a13);
            }
            float eq0 = expf(acs_s[b32 + q2] - base);
            float eq1 = expf(acs_s[b32 + q2 + 16] - base);
            for (int n = 0; n < NS; n++) {
                float c0 = Cs[q2*68 + n] * eq0;
                float c1 = Cs[(q2+16)*68 + n] * eq1;
                float h0 = H[(p4+0)*65 + n];
                float h1 = H[(p4+1)*65 + n];
                float h2 = H[(p4+2)*65 + n];
                float h3 = H[(p4+3)*65 + n];
                a00 = fmaf(c0,h0,a00); a01 = fmaf(c0,h1,a01);
                a02 = fmaf(c0,h2,a02); a03 = fmaf(c0,h3,a03);
                a10 = fmaf(c1,h0,a10); a11 = fmaf(c1,h1,a11);
                a12 = fmaf(c1,h2,a12); a13 = fmaf(c1,h3,a13);
            }
            float y00 = (a00 + Dh * xs[q2*132 + p4+0]) * (pZ0.x / (1.f + expf(-pZ0.x)));
            float y01 = (a01 + Dh * xs[q2*132 + p4+1]) * (pZ0.y / (1.f + expf(-pZ0.y)));
            float y02 = (a02 + Dh * xs[q2*132 + p4+2]) * (pZ0.z / (1.f + expf(-pZ0.z)));
            float y03 = (a03 + Dh * xs[q2*132 + p4+3]) * (pZ0.w / (1.f + expf(-pZ0.w)));
            float y10 = (a10 + Dh * xs[(q2+16)*132 + p4+0]) * (pZ1.x / (1.f + expf(-pZ1.x)));
            float y11 = (a11 + Dh * xs[(q2+16)*132 + p4+1]) * (pZ1.y / (1.f + expf(-pZ1.y)));
            float y12 = (a12 + Dh * xs[(q2+16)*132 + p4+2]) * (pZ1.z / (1.f + expf(-pZ1.z)));
            float y13 = (a13 + Dh * xs[(q2+16)*132 + p4+3]) * (pZ1.w / (1.f + expf(-pZ1.w)));
            unsigned short* yb0 = (unsigned short*)(zy + (rowbase + b32 + q2) * DPROJ + DI);
            unsigned short* yb1 = (unsigned short*)(zy + (rowbase + b32 + q2 + 16) * DPROJ + DI);
            ushort4 h4, l4;
            bsplit(y00, h4.x, l4.x); bsplit(y01, h4.y, l4.y);
            bsplit(y02, h4.z, l4.z); bsplit(y03, h4.w, l4.w);
            *(ushort4*)(yb0 + h * HD + p4)        = h4;
            *(ushort4*)(yb0 + 2048 + h * HD + p4) = l4;
            bsplit(y10, h4.x, l4.x); bsplit(y11, h4.y, l4.y);
            bsplit(y12, h4.z, l4.z); bsplit(y13, h4.w, l4.w);
            *(ushort4*)(yb1 + h * HD + p4)        = h4;
            *(ushort4*)(yb1 + 2048 + h * HD + p4) = l4;
        }
        __syncthreads();

        {
            float decay = expf(aL - base);
            float hreg[16];
            #pragma unroll
            for (int j = 0; j < 16; j++)
                hreg[j] = H[pp*65 + n0 + j] * decay;
            for (int t = 0; t < 32; t++) {
                float xa = xs[t*132 + pp] * coefs[t];
                #pragma unroll
                for (int j = 0; j < 16; j++)
                    hreg[j] = fmaf(xa, Bsh[t*68 + n0 + j], hreg[j]);
            }
            #pragma unroll
            for (int j = 0; j < 16; j++)
                H[pp*65 + n0 + j] = hreg[j];
        }
        __syncthreads();
    }
}

extern "C" void kernel_launch(void* const* d_in, const int* in_sizes, int n_in,
                              void* d_out, int out_size, void* d_ws, size_t ws_size,
                              hipStream_t stream)
{
    const float* x       = (const float*)d_in[0];
    const float* W_in    = (const float*)d_in[1];
    const float* conv_w  = (const float*)d_in[2];
    const float* conv_b  = (const float*)d_in[3];
    const float* A_log   = (const float*)d_in[4];
    const float* dt_bias = (const float*)d_in[5];
    const float* D_skip  = (const float*)d_in[6];
    const float* W_out   = (const float*)d_in[7];
    float* out = (float*)d_out;

    // workspace (~136 MB)
    float* proj   = (float*)d_ws;                          // L_*DPROJ
    float* xbc    = proj   + (size_t)L_ * DPROJ;           // L_*CONVD (also hosts XH/XL)
    float* dt_t   = xbc    + (size_t)L_ * CONVD;           // NC*NH*T_
    float* acs    = dt_t   + (size_t)NC * NH * T_;
    float* states = acs    + (size_t)NC * NH * T_;         // NC*NH*HD*NS
    unsigned short* WinH  = (unsigned short*)(states + (size_t)NC * NH * HD * NS);
    unsigned short* WinL  = WinH  + (size_t)NPADIN * DM;
    unsigned short* WoutH = WinL  + (size_t)NPADIN * DM;
    unsigned short* WoutL = WoutH + (size_t)DM * DI;
    unsigned short* XH = (unsigned short*)xbc;             // transient, dead before conv_silu
    unsigned short* XL = XH + (size_t)L_ * DM;
    unsigned short* projU = (unsigned short*)proj;

    dim3 blk(256);
    {   // one-time weight splits (W_in padded to NPADIN rows with zeros)
        int s4in = (DPROJ * DM) / 4, d4in = (NPADIN * DM) / 4;
        split_pad<<<dim3((d4in + 255) / 256), blk, 0, stream>>>(W_in, WinH, WinL, s4in, d4in);
        int n4out = (DM * DI) / 4;
        split_pad<<<dim3((n4out + 255) / 256), blk, 0, stream>>>(W_out, WoutH, WoutL, n4out, n4out);
    }

    for (int b = 0; b < B_; b++) {
        const float* xb = x + (size_t)b * L_ * DM;
        float* outb = out + (size_t)b * L_ * DM;
        int x4 = (L_ * DM) / 4;
        split_pad<<<dim3((x4 + 255) / 256), blk, 0, stream>>>(xb, XH, XL, x4, x4);
        mfma_gemm_lds<<<dim3((NPADIN / 128) * (L_ / 128)), blk, 0, stream>>>(
            XH, XL, (long)DM, WinH, WinL, proj, DPROJ, DM, DPROJ, L_ / 128);
        conv_silu<<<dim3((unsigned)(((size_t)L_ * CONVD + 255) / 256)), blk, 0, stream>>>(
            proj, conv_w, conv_b, xbc);
        dt_scan<<<dim3(NC * NH), blk, 0, stream>>>(proj, A_log, dt_bias, dt_t, acs);
        chunk_states<<<dim3(NC * NH), blk, 0, stream>>>(xbc, dt_t, acs, states);
        prev_rec<<<dim3(NH * 4), blk, 0, stream>>>(states, acs);
        y_chunk<<<dim3(NC * NH), dim3(512), 0, stream>>>(xbc, dt_t, acs, states, D_skip, proj);
        // out-proj: A = split Y inside proj rows (hi at +DI*2 ushorts, lo at +DI*2+2048)
        mfma_gemm_lds<<<dim3((DM / 128) * (L_ / 128)), blk, 0, stream>>>(
            projU + (size_t)DI * 2, projU + (size_t)DI * 2 + 2048, (long)(DPROJ * 2),
            WoutH, WoutL, outb, DM, DI, DM, L_ / 128);
    }
}

// Round 15
// 761.675 us; speedup vs baseline: 1.5212x; 1.0075x over previous
//
#include <hip/hip_runtime.h>

#define B_     2
#define L_     4096
#define DM     1024
#define DI     2048
#define NH     16
#define HD     128
#define NS     64      // D_STATE
#define T_     256     // CHUNK
#define NC     16      // L_/T_
#define CONVD  2176    // DI + 2*NS
#define DPROJ  4240    // DI + CONVD + NH
#define NPADIN 4352    // 34*128, padded W_in rows

typedef __attribute__((ext_vector_type(8))) short bf16x8;
typedef __attribute__((ext_vector_type(4))) float f32x4;

// split fp32 -> bf16 hi (RNE) + bf16 lo (truncated residual)
__device__ __forceinline__ void bsplit(float x, unsigned short& h, unsigned short& l) {
    unsigned u = __float_as_uint(x);
    unsigned t = u + 0x7FFFu + ((u >> 16) & 1u);
    h = (unsigned short)(t >> 16);
    float lo = x - __uint_as_float(t & 0xFFFF0000u);
    l = (unsigned short)(__float_as_uint(lo) >> 16);
}

// async global->LDS 16B (DMA). LDS dest = wave-uniform base + lane*16 (linear chunks).
__device__ __forceinline__ void glds16(const unsigned short* g, unsigned short* l) {
    __builtin_amdgcn_global_load_lds(
        (const __attribute__((address_space(1))) void*)g,
        (__attribute__((address_space(3))) void*)l, 16, 0, 0);
}

// ---------------- split fp32 matrix -> bf16 hi/lo, zero-padding tail rows ----------------
__global__ __launch_bounds__(256) void split_pad(
    const float* __restrict__ W, unsigned short* __restrict__ Wh,
    unsigned short* __restrict__ Wl, int srcN4, int dstN4)
{
    int i = blockIdx.x * 256 + threadIdx.x;
    if (i >= dstN4) return;
    ushort4 h = {0,0,0,0}, l = {0,0,0,0};
    if (i < srcN4) {
        float4 v = *(const float4*)(W + (size_t)i * 4);
        bsplit(v.x, h.x, l.x); bsplit(v.y, h.y, l.y);
        bsplit(v.z, h.z, l.z); bsplit(v.w, h.w, l.w);
    }
    *(ushort4*)(Wh + (size_t)i * 4) = h;
    *(ushort4*)(Wl + (size_t)i * 4) = l;
}

// ---------------- LDS-staged bf16x3 GEMM; gload_lds staging + source-side chunk swizzle ----------------
// Placement P(row,f) = row*4 + ((f + (row>>1)) & 3)  (bijective per row's 4 chunks).
// DMA keeps LDS linear; each lane's GLOBAL source picks the inverse-swizzled k-chunk.
// Fragment reads then hit each bank-quad group exactly 2x (free) instead of 8-way.
__global__ __launch_bounds__(256, 2) void mfma_gemm_lds(
    const unsigned short* __restrict__ Ah, const unsigned short* __restrict__ Al,
    long arow, const unsigned short* __restrict__ Wh, const unsigned short* __restrict__ Wl,
    float* __restrict__ C, int N, int K, int ldc, int nyt)
{
    __shared__ unsigned short AhL[128 * 32];
    __shared__ unsigned short AlL[128 * 32];
    __shared__ unsigned short BhL[128 * 32];
    __shared__ unsigned short BlL[128 * 32];

    // XCD-chunked column-major tiling
    int NB = gridDim.x;
    int bid = blockIdx.x;
    int t = (bid & 7) * (NB >> 3) + (bid >> 3);
    int xt = t / nyt, yt = t % nyt;
    int tid = threadIdx.x;
    int lane = tid & 63, w = tid >> 6;
    int m0 = yt * 128, n0 = xt * 128;
    int mblk = (w >> 1) * 64, nblk = (w & 1) * 64;
    int fr = lane & 15;
    int fq = lane >> 4;            // k-fragment group (0..3)

    // staging: LDS chunk ci (linear) holds logical (row = ci>>2, f = ((ci&3)-(ci>>3)) & 3)
    int r0 = tid >> 2,         kc0 = ((((tid) & 3) - ((tid) >> 3)) & 3) * 8;
    int r1 = (tid + 256) >> 2, kc1 = ((((tid + 256) & 3) - ((tid + 256) >> 3)) & 3) * 8;
    int lo0 = tid * 8;           // ushort offset in LDS (= 16B * chunk)
    int lo1 = (tid + 256) * 8;

    // fragment LDS offsets (k-invariant): chunk = row*4 + ((fq + (row>>1)) & 3)
    int offA[4], offB[4];
    #pragma unroll
    for (int tt = 0; tt < 4; tt++) {
        int ra = mblk + tt*16 + fr;
        int rb = nblk + tt*16 + fr;
        offA[tt] = ra * 32 + ((fq + (ra >> 1)) & 3) * 8;
        offB[tt] = rb * 32 + ((fq + (rb >> 1)) & 3) * 8;
    }

    f32x4 acc[4][4];
    #pragma unroll
    for (int i = 0; i < 4; i++)
        #pragma unroll
        for (int j = 0; j < 4; j++) acc[i][j] = (f32x4){0.f, 0.f, 0.f, 0.f};

    int nk = K >> 5;
    for (int ks = 0; ks < nk; ks++) {
        int k0 = ks << 5;
        __syncthreads();   // previous tile's frag reads done before DMA overwrites
        {
            size_t a0 = (size_t)(m0 + r0) * arow + k0 + kc0;
            size_t a1 = (size_t)(m0 + r1) * arow + k0 + kc1;
            size_t b0 = (size_t)(n0 + r0) * K + k0 + kc0;
            size_t b1 = (size_t)(n0 + r1) * K + k0 + kc1;
            glds16(Ah + a0, AhL + lo0);
            glds16(Ah + a1, AhL + lo1);
            glds16(Al + a0, AlL + lo0);
            glds16(Al + a1, AlL + lo1);
            glds16(Wh + b0, BhL + lo0);
            glds16(Wh + b1, BhL + lo1);
            glds16(Wl + b0, BlL + lo0);
            glds16(Wl + b1, BlL + lo1);
        }
        __syncthreads();   // barrier drains vmcnt -> DMA data visible

        bf16x8 ah[4], al[4], bh[4], bl[4];
        #pragma unroll
        for (int tt = 0; tt < 4; tt++) {
            ah[tt] = *(const bf16x8*)&AhL[offA[tt]];
            al[tt] = *(const bf16x8*)&AlL[offA[tt]];
            bh[tt] = *(const bf16x8*)&BhL[offB[tt]];
            bl[tt] = *(const bf16x8*)&BlL[offB[tt]];
        }
        #pragma unroll
        for (int mt = 0; mt < 4; mt++)
            #pragma unroll
            for (int nt = 0; nt < 4; nt++) {
                f32x4 a = acc[mt][nt];
                a = __builtin_amdgcn_mfma_f32_16x16x32_bf16(al[mt], bh[nt], a, 0, 0, 0);
                a = __builtin_amdgcn_mfma_f32_16x16x32_bf16(ah[mt], bl[nt], a, 0, 0, 0);
                a = __builtin_amdgcn_mfma_f32_16x16x32_bf16(ah[mt], bh[nt], a, 0, 0, 0);
                acc[mt][nt] = a;
            }
    }

    int crow = fq * 4;
    #pragma unroll
    for (int mt = 0; mt < 4; mt++) {
        int rbase = m0 + mblk + mt*16 + crow;
        #pragma unroll
        for (int nt = 0; nt < 4; nt++) {
            int col = n0 + nblk + nt*16 + fr;
            if (col < N) {
                #pragma unroll
                for (int i = 0; i < 4; i++)
                    C[(size_t)(rbase + i) * ldc + col] = acc[mt][nt][i];
            }
        }
    }
}

// ---------------- depthwise causal conv (width 4) + bias + silu; one batch (r10 exact) ----------------
__global__ void conv_silu(const float* __restrict__ proj, const float* __restrict__ w,
                          const float* __restrict__ bias, float* __restrict__ xbc)
{
    size_t idx = (size_t)blockIdx.x * 256 + threadIdx.x;
    if (idx >= (size_t)L_ * CONVD) return;
    int c = (int)(idx % CONVD);
    int l = (int)(idx / CONVD);
    float acc = bias[c];
    #pragma unroll
    for (int j = 0; j < 4; j++) {
        int ll = l - 3 + j;
        if (ll >= 0)
            acc = fmaf(proj[(size_t)ll * DPROJ + DI + c], w[c*4+j], acc);
    }
    acc = acc / (1.f + expf(-acc));   // silu
    xbc[(size_t)l * CONVD + c] = acc;
}

// ---------------- dt = softplus(dt_raw + bias); acs = cumsum(dt*A) within 256-chunk ----------------
__global__ __launch_bounds__(256) void dt_scan(
    const float* __restrict__ proj, const float* __restrict__ A_log,
    const float* __restrict__ dt_bias, float* __restrict__ dt_t, float* __restrict__ acs)
{
    int blk = blockIdx.x;            // c*NH + h
    int h = blk % NH;
    int c = blk / NH;
    int t = threadIdx.x;
    size_t row = (size_t)(c * T_ + t);
    float raw = proj[row * DPROJ + DI + CONVD + h] + dt_bias[h];
    float dtv = (raw > 20.f) ? raw : log1pf(expf(raw));
    float Ah = -expf(A_log[h]);
    __shared__ float buf[T_];
    buf[t] = dtv * Ah;
    __syncthreads();
    for (int off = 1; off < T_; off <<= 1) {
        float add = (t >= off) ? buf[t - off] : 0.f;
        __syncthreads();
        buf[t] += add;
        __syncthreads();
    }
    size_t o = (size_t)blk * T_ + t;
    dt_t[o] = dtv;
    acs[o]  = buf[t];
}

// ---------------- per-256-chunk states[p][n] = sum_t x[t,p]*B[t,n]*exp(acs_last-acs[t])*dt[t] ----------------
__global__ __launch_bounds__(256) void chunk_states(
    const float* __restrict__ xbc, const float* __restrict__ dt_t,
    const float* __restrict__ acs, float* __restrict__ states)
{
    int bid = blockIdx.x;            // XCD swizzle (grid 256)
    int blk = (bid & 7) * 32 + (bid >> 3);
    int h = blk % NH;
    int c = blk / NH;
    int tid = threadIdx.x;
    __shared__ float coef[T_];
    __shared__ __align__(16) float xs[32][HD];
    __shared__ float Bs[32][NS + 1];
    {
        size_t o = (size_t)blk * T_;
        float last = acs[o + T_ - 1];
        coef[tid] = expf(last - acs[o + tid]) * dt_t[o + tid];
    }
    __syncthreads();
    int tx = tid % 16;
    int ty = tid / 16;
    float acc[8][4];
    #pragma unroll
    for (int i = 0; i < 8; i++)
        #pragma unroll
        for (int j = 0; j < 4; j++) acc[i][j] = 0.f;
    size_t rowbase = (size_t)(c * T_);
    for (int t0 = 0; t0 < T_; t0 += 32) {
        #pragma unroll
        for (int i = 0; i < 4; i++) {
            int idx = tid + 256 * i;
            int r = idx >> 5, cv = idx & 31;
            float4 v = *(const float4*)(xbc + (rowbase + t0 + r) * CONVD + h * HD + cv * 4);
            *(float4*)&xs[r][cv * 4] = v;
        }
        #pragma unroll
        for (int i = 0; i < 2; i++) {
            int idx = tid + 256 * i;
            int r = idx >> 4, cv = idx & 15;
            float4 v = *(const float4*)(xbc + (rowbase + t0 + r) * CONVD + DI + cv * 4);
            float wc = coef[t0 + r];
            Bs[r][cv*4+0] = v.x * wc; Bs[r][cv*4+1] = v.y * wc;
            Bs[r][cv*4+2] = v.z * wc; Bs[r][cv*4+3] = v.w * wc;
        }
        __syncthreads();
        #pragma unroll
        for (int tt = 0; tt < 32; tt++) {
            float xv[8], bv[4];
            #pragma unroll
            for (int i = 0; i < 8; i++) xv[i] = xs[tt][ty*8+i];
            #pragma unroll
            for (int j = 0; j < 4; j++) bv[j] = Bs[tt][tx*4+j];
            #pragma unroll
            for (int i = 0; i < 8; i++)
                #pragma unroll
                for (int j = 0; j < 4; j++)
                    acc[i][j] = fmaf(xv[i], bv[j], acc[i][j]);
        }
        __syncthreads();
    }
    size_t base = (size_t)blk * HD * NS;
    #pragma unroll
    for (int i = 0; i < 8; i++)
        #pragma unroll
        for (int j = 0; j < 4; j++)
            states[base + (size_t)(ty*8+i) * NS + tx*4+j] = acc[i][j];
}

// ---------------- in-place inter-chunk recurrence: states[c] <- prev[c] ----------------
__global__ __launch_bounds__(256) void prev_rec(
    float* __restrict__ states, const float* __restrict__ acs)
{
    int blk = blockIdx.x;          // h*4 + pq
    int pq = blk % 4;
    int h = blk / 4;
    int tid = threadIdx.x;
    int s = tid * 8;
    int p = pq * 32 + s / NS;
    int n0 = s % NS;
    float run[8];
    #pragma unroll
    for (int j = 0; j < 8; j++) run[j] = 0.f;
    for (int c = 0; c < NC; c++) {
        size_t ch = (size_t)(c * NH + h);
        size_t off = ch * HD * NS + (size_t)p * NS + n0;
        float sv[8];
        #pragma unroll
        for (int j = 0; j < 8; j++) sv[j] = states[off + j];
        #pragma unroll
        for (int j = 0; j < 8; j++) states[off + j] = run[j];
        float f = expf(acs[ch * T_ + T_ - 1]);
        #pragma unroll
        for (int j = 0; j < 8; j++) run[j] = sv[j] + f * run[j];
    }
}

// ---------------- fused Y per (chunk,head); gated output written as SPLIT bf16 (r10 exact) ----------------
__global__ __launch_bounds__(512, 2) void y_chunk(
    const float* __restrict__ xbc, const float* __restrict__ dt_t,
    const float* __restrict__ acs, const float* __restrict__ prev,
    const float* __restrict__ D_skip, float* zy /* = proj */)
{
    int bid = blockIdx.x;
    int l = (bid & 7) * 32 + (bid >> 3);   // XCD swizzle
    int h = l & 15;
    int c = l >> 4;
    int tid = threadIdx.x;

    __shared__ __align__(16) float smem[18496];
    float* H     = smem;            // [128][65]
    float* Cs    = smem + 8320;     // [32][68]
    float* Bsh   = smem + 10496;    // [32][68]
    float* xs    = smem + 12672;    // [32][132]
    float* Ss    = smem + 16896;    // [32][33]
    float* acs_s = smem + 17952;    // [256]
    float* dts   = smem + 18208;    // [256]
    float* coefs = smem + 18464;    // [32]

    size_t bch = (size_t)(c * NH + h);
    size_t rowbase = (size_t)(c * T_);
    if (tid < 256) {
        acs_s[tid] = acs[bch * T_ + tid];
        dts[tid]   = dt_t[bch * T_ + tid];
    }

    float4 pB, pC, pX0, pX1;
    int rBC = tid >> 4, cBC = (tid & 15) * 4;
    int rX0 = tid >> 5, cX0 = (tid & 31) * 4;
    int rX1 = (tid + 512) >> 5;
    auto issue = [&](int s) {
        const float* base = xbc + (rowbase + s * 32) * CONVD;
        pB  = *(const float4*)(base + (size_t)rBC * CONVD + DI + cBC);
        pC  = *(const float4*)(base + (size_t)rBC * CONVD + DI + NS + cBC);
        pX0 = *(const float4*)(base + (size_t)rX0 * CONVD + h * HD + cX0);
        pX1 = *(const float4*)(base + (size_t)rX1 * CONVD + h * HD + cX0);
    };
    issue(0);

    int pp = tid >> 2, n0 = (tid & 3) * 16;
    {
        const float* src = prev + bch * (HD * NS) + (size_t)pp * NS + n0;
        #pragma unroll
        for (int j4 = 0; j4 < 4; j4++) {
            float4 v = *(const float4*)(src + j4 * 4);
            H[pp*65 + n0 + j4*4 + 0] = v.x;
            H[pp*65 + n0 + j4*4 + 1] = v.y;
            H[pp*65 + n0 + j4*4 + 2] = v.z;
            H[pp*65 + n0 + j4*4 + 3] = v.w;
        }
    }
    __syncthreads();

    float Dh = D_skip[h];
    int q2 = tid & 15;
    int p4 = (tid >> 4) * 4;
    int kq = tid >> 4;
    int kk0 = tid & 15;

    for (int s = 0; s < 8; s++) {
        int b32 = s * 32;
        float base = (s == 0) ? 0.f : acs_s[b32 - 1];
        float aL = acs_s[b32 + 31];

        *(float4*)&Bsh[rBC * 68 + cBC]  = pB;
        *(float4*)&Cs [rBC * 68 + cBC]  = pC;
        *(float4*)&xs [rX0 * 132 + cX0] = pX0;
        *(float4*)&xs [rX1 * 132 + cX0] = pX1;
        if (tid < 32)
            coefs[tid] = dts[b32 + tid] * expf(aL - acs_s[b32 + tid]);
        __syncthreads();

        if (s < 7) issue(s + 1);
        float4 pZ0 = *(const float4*)(zy + (rowbase + b32 + q2) * DPROJ + h * HD + p4);
        float4 pZ1 = *(const float4*)(zy + (rowbase + b32 + q2 + 16) * DPROJ + h * HD + p4);

        {
            float sv0 = 0.f, sv1 = 0.f;
            for (int n = 0; n < NS; n++) {
                float cq = Cs[kq * 68 + n];
                sv0 = fmaf(cq, Bsh[kk0 * 68 + n], sv0);
                sv1 = fmaf(cq, Bsh[(kk0 + 16) * 68 + n], sv1);
            }
            float v0 = 0.f, v1 = 0.f;
            if (kq >= kk0)
                v0 = sv0 * expf(acs_s[b32+kq] - acs_s[b32+kk0]) * dts[b32+kk0];
            if (kq >= kk0+16)
                v1 = sv1 * expf(acs_s[b32+kq] - acs_s[b32+kk0+16]) * dts[b32+kk0+16];
            Ss[kq * 33 + kk0]      = v0;
            Ss[kq * 33 + kk0 + 16] = v1;
        }
        __syncthreads();

        {
            float a00=0.f,a01=0.f,a02=0.f,a03=0.f;
            float a10=0.f,a11=0.f,a12=0.f,a13=0.f;
            for (int kk = 0; kk < 32; kk++) {
                float s0 = Ss[q2 * 33 + kk];
                float s1 = Ss[(q2+16) * 33 + kk];
                float x0 = xs[kk*132 + p4 + 0];
                float x1 = xs[kk*132 + p4 + 1];
                float x2 = xs[kk*132 + p4 + 2];
                float x3 = xs[kk*132 + p4 + 3];
                a00 = fmaf(s0,x0,a00); a01 = fmaf(s0,x1,a01);
                a02 = fmaf(s0,x2,a02); a03 = fmaf(s0,x3,a03);
                a10 = fmaf(s1,x0,a10); a11 = fmaf(s1,x1,a11);
                a12 = fmaf(s1,x2,a12); a13 = fmaf(s1,x3,a13);
            }
            float eq0 = expf(acs_s[b32 + q2] - base);
            float eq1 = expf(acs_s[b32 + q2 + 16] - base);
            for (int n = 0; n < NS; n++) {
                float c0 = Cs[q2*68 + n] * eq0;
                float c1 = Cs[(q2+16)*68 + n] * eq1;
                float h0 = H[(p4+0)*65 + n];
                float h1 = H[(p4+1)*65 + n];
                float h2 = H[(p4+2)*65 + n];
                float h3 = H[(p4+3)*65 + n];
                a00 = fmaf(c0,h0,a00); a01 = fmaf(c0,h1,a01);
                a02 = fmaf(c0,h2,a02); a03 = fmaf(c0,h3,a03);
                a10 = fmaf(c1,h0,a10); a11 = fmaf(c1,h1,a11);
                a12 = fmaf(c1,h2,a12); a13 = fmaf(c1,h3,a13);
            }
            float y00 = (a00 + Dh * xs[q2*132 + p4+0]) * (pZ0.x / (1.f + expf(-pZ0.x)));
            float y01 = (a01 + Dh * xs[q2*132 + p4+1]) * (pZ0.y / (1.f + expf(-pZ0.y)));
            float y02 = (a02 + Dh * xs[q2*132 + p4+2]) * (pZ0.z / (1.f + expf(-pZ0.z)));
            float y03 = (a03 + Dh * xs[q2*132 + p4+3]) * (pZ0.w / (1.f + expf(-pZ0.w)));
            float y10 = (a10 + Dh * xs[(q2+16)*132 + p4+0]) * (pZ1.x / (1.f + expf(-pZ1.x)));
            float y11 = (a11 + Dh * xs[(q2+16)*132 + p4+1]) * (pZ1.y / (1.f + expf(-pZ1.y)));
            float y12 = (a12 + Dh * xs[(q2+16)*132 + p4+2]) * (pZ1.z / (1.f + expf(-pZ1.z)));
            float y13 = (a13 + Dh * xs[(q2+16)*132 + p4+3]) * (pZ1.w / (1.f + expf(-pZ1.w)));
            unsigned short* yb0 = (unsigned short*)(zy + (rowbase + b32 + q2) * DPROJ + DI);
            unsigned short* yb1 = (unsigned short*)(zy + (rowbase + b32 + q2 + 16) * DPROJ + DI);
            ushort4 h4, l4;
            bsplit(y00, h4.x, l4.x); bsplit(y01, h4.y, l4.y);
            bsplit(y02, h4.z, l4.z); bsplit(y03, h4.w, l4.w);
            *(ushort4*)(yb0 + h * HD + p4)        = h4;
            *(ushort4*)(yb0 + 2048 + h * HD + p4) = l4;
            bsplit(y10, h4.x, l4.x); bsplit(y11, h4.y, l4.y);
            bsplit(y12, h4.z, l4.z); bsplit(y13, h4.w, l4.w);
            *(ushort4*)(yb1 + h * HD + p4)        = h4;
            *(ushort4*)(yb1 + 2048 + h * HD + p4) = l4;
        }
        __syncthreads();

        {
            float decay = expf(aL - base);
            float hreg[16];
            #pragma unroll
            for (int j = 0; j < 16; j++)
                hreg[j] = H[pp*65 + n0 + j] * decay;
            for (int t = 0; t < 32; t++) {
                float xa = xs[t*132 + pp] * coefs[t];
                #pragma unroll
                for (int j = 0; j < 16; j++)
                    hreg[j] = fmaf(xa, Bsh[t*68 + n0 + j], hreg[j]);
            }
            #pragma unroll
            for (int j = 0; j < 16; j++)
                H[pp*65 + n0 + j] = hreg[j];
        }
        __syncthreads();
    }
}

extern "C" void kernel_launch(void* const* d_in, const int* in_sizes, int n_in,
                              void* d_out, int out_size, void* d_ws, size_t ws_size,
                              hipStream_t stream)
{
    const float* x       = (const float*)d_in[0];
    const float* W_in    = (const float*)d_in[1];
    const float* conv_w  = (const float*)d_in[2];
    const float* conv_b  = (const float*)d_in[3];
    const float* A_log   = (const float*)d_in[4];
    const float* dt_bias = (const float*)d_in[5];
    const float* D_skip  = (const float*)d_in[6];
    const float* W_out   = (const float*)d_in[7];
    float* out = (float*)d_out;

    // workspace (~136 MB)
    float* proj   = (float*)d_ws;                          // L_*DPROJ
    float* xbc    = proj   + (size_t)L_ * DPROJ;           // L_*CONVD (also hosts XH/XL)
    float* dt_t   = xbc    + (size_t)L_ * CONVD;           // NC*NH*T_
    float* acs    = dt_t   + (size_t)NC * NH * T_;
    float* states = acs    + (size_t)NC * NH * T_;         // NC*NH*HD*NS
    unsigned short* WinH  = (unsigned short*)(states + (size_t)NC * NH * HD * NS);
    unsigned short* WinL  = WinH  + (size_t)NPADIN * DM;
    unsigned short* WoutH = WinL  + (size_t)NPADIN * DM;
    unsigned short* WoutL = WoutH + (size_t)DM * DI;
    unsigned short* XH = (unsigned short*)xbc;             // transient, dead before conv_silu
    unsigned short* XL = XH + (size_t)L_ * DM;
    unsigned short* projU = (unsigned short*)proj;

    dim3 blk(256);
    {   // one-time weight splits (W_in padded to NPADIN rows with zeros)
        int s4in = (DPROJ * DM) / 4, d4in = (NPADIN * DM) / 4;
        split_pad<<<dim3((d4in + 255) / 256), blk, 0, stream>>>(W_in, WinH, WinL, s4in, d4in);
        int n4out = (DM * DI) / 4;
        split_pad<<<dim3((n4out + 255) / 256), blk, 0, stream>>>(W_out, WoutH, WoutL, n4out, n4out);
    }

    for (int b = 0; b < B_; b++) {
        const float* xb = x + (size_t)b * L_ * DM;
        float* outb = out + (size_t)b * L_ * DM;
        int x4 = (L_ * DM) / 4;
        split_pad<<<dim3((x4 + 255) / 256), blk, 0, stream>>>(xb, XH, XL, x4, x4);
        mfma_gemm_lds<<<dim3((NPADIN / 128) * (L_ / 128)), blk, 0, stream>>>(
            XH, XL, (long)DM, WinH, WinL, proj, DPROJ, DM, DPROJ, L_ / 128);
        conv_silu<<<dim3((unsigned)(((size_t)L_ * CONVD + 255) / 256)), blk, 0, stream>>>(
            proj, conv_w, conv_b, xbc);
        dt_scan<<<dim3(NC * NH), blk, 0, stream>>>(proj, A_log, dt_bias, dt_t, acs);
        chunk_states<<<dim3(NC * NH), blk, 0, stream>>>(xbc, dt_t, acs, states);
        prev_rec<<<dim3(NH * 4), blk, 0, stream>>>(states, acs);
        y_chunk<<<dim3(NC * NH), dim3(512), 0, stream>>>(xbc, dt_t, acs, states, D_skip, proj);
        // out-proj: A = split Y inside proj rows (hi at +DI*2 ushorts, lo at +DI*2+2048)
        mfma_gemm_lds<<<dim3((DM / 128) * (L_ / 128)), blk, 0, stream>>>(
            projU + (size_t)DI * 2, projU + (size_t)DI * 2 + 2048, (long)(DPROJ * 2),
            WoutH, WoutL, outb, DM, DI, DM, L_ / 128);
    }
}